// Round 1
// baseline (1825.708 us; speedup 1.0000x reference)
//
#include <hip/hip_runtime.h>

#define NPOS 16384   // H*W
#define SCALEQ 0.17677669529663687f  // 32^-0.5
#define EPSV 1e-5f

// ---------------- Kernel A: context accumulation ----------------
// grid = B*32 (512), block = 256. Each block: 512 positions of one batch.
// ctxT layout: [b][h][e][d]  (B*4*32*32 floats in d_ws, pre-zeroed)
__global__ __launch_bounds__(256) void kctx(const float* __restrict__ x,
                                            const float* __restrict__ wq,
                                            float* __restrict__ ctxT) {
  __shared__ float kT[32 * 256];  // [d][p], XOR-swizzled p^2d
  __shared__ float vT[32 * 256];  // [e][p], linear
  const int t = threadIdx.x;
  const int b = blockIdx.x >> 5;
  const int tile = blockIdx.x & 31;
  const int d0 = (t & 15) << 1;
  const int e0 = (t >> 4) << 1;
  float acc[4][2][2];
#pragma unroll
  for (int h = 0; h < 4; ++h)
#pragma unroll
    for (int i = 0; i < 2; ++i)
#pragma unroll
      for (int j = 0; j < 2; ++j) acc[h][i][j] = 0.f;

  for (int chunk = 0; chunk < 2; ++chunk) {
    const int p = (tile << 9) + (chunk << 8) + t;
    float xr[64];
#pragma unroll
    for (int c = 0; c < 64; ++c)
      xr[c] = x[((size_t)(b * 64 + c) << 14) + p];

#pragma unroll
    for (int h = 0; h < 4; ++h) {
      // ---- k projection (channels 128 + h*32 + i) ----
      float kk[32];
#pragma unroll
      for (int i = 0; i < 32; ++i) {
        const float* wr = wq + (128 + h * 32 + i) * 64;
        float a = 0.f;
#pragma unroll
        for (int c = 0; c < 64; ++c) a = fmaf(wr[c], xr[c], a);
        kk[i] = a;
      }
      // softmax over the 32 head features (thread-local)
      float m = kk[0];
#pragma unroll
      for (int i = 1; i < 32; ++i) m = fmaxf(m, kk[i]);
      float s = 0.f;
#pragma unroll
      for (int i = 0; i < 32; ++i) { kk[i] = __expf(kk[i] - m); s += kk[i]; }
      const float inv = 1.f / s;

      // ---- v projection (channels 256 + h*32 + i) ----
      float vv[32];
#pragma unroll
      for (int i = 0; i < 32; ++i) {
        const float* wr = wq + (256 + h * 32 + i) * 64;
        float a = 0.f;
#pragma unroll
        for (int c = 0; c < 64; ++c) a = fmaf(wr[c], xr[c], a);
        vv[i] = a;
      }

      __syncthreads();  // protect previous phase-2 reads
#pragma unroll
      for (int i = 0; i < 32; ++i) kT[i * 256 + (t ^ (2 * i))] = kk[i] * inv;
#pragma unroll
      for (int i = 0; i < 32; ++i) vT[i * 256 + t] = vv[i];
      __syncthreads();

      // ---- phase 2: ctx[d,e] += sum_p k[d][p]*v[e][p], 2x2 tile/thread ----
#pragma unroll 2
      for (int p2 = 0; p2 < 256; p2 += 2) {
        const float2 k0 = *(const float2*)&kT[d0 * 256 + (p2 ^ (2 * d0))];
        const float2 k1 = *(const float2*)&kT[(d0 + 1) * 256 + (p2 ^ (2 * (d0 + 1)))];
        const float2 v0 = *(const float2*)&vT[e0 * 256 + p2];
        const float2 v1 = *(const float2*)&vT[(e0 + 1) * 256 + p2];
        acc[h][0][0] += k0.x * v0.x + k0.y * v0.y;
        acc[h][0][1] += k0.x * v1.x + k0.y * v1.y;
        acc[h][1][0] += k1.x * v0.x + k1.y * v0.y;
        acc[h][1][1] += k1.x * v1.x + k1.y * v1.y;
      }
    }
  }
#pragma unroll
  for (int h = 0; h < 4; ++h)
#pragma unroll
    for (int i = 0; i < 2; ++i)
#pragma unroll
      for (int j = 0; j < 2; ++j)
        atomicAdd(&ctxT[(((b * 4 + h) * 32) + (e0 + j)) * 32 + (d0 + i)],
                  acc[h][i][j]);
}

// ---------------- Kernel B: q path + attention out + out-projection ----------
// grid = B*64 (1024), block = 256. Writes pre-BN y into d_out.
__global__ __launch_bounds__(256) void kout(const float* __restrict__ x,
                                            const float* __restrict__ wq,
                                            const float* __restrict__ wo,
                                            const float* __restrict__ bo,
                                            const float* __restrict__ ctxT,
                                            float* __restrict__ y) {
  __shared__ float cl[4096];  // ctx for this batch: [h][e][d]
  const int t = threadIdx.x;
  const int b = blockIdx.x >> 6;
  const int tile = blockIdx.x & 63;
  const int p = (tile << 8) + t;
#pragma unroll
  for (int i = 0; i < 16; ++i) cl[i * 256 + t] = ctxT[(b << 12) + i * 256 + t];
  __syncthreads();

  float xr[64];
#pragma unroll
  for (int c = 0; c < 64; ++c) xr[c] = x[((size_t)(b * 64 + c) << 14) + p];

  float y0[64];
#pragma unroll
  for (int o = 0; o < 64; ++o) y0[o] = 0.f;

  for (int h = 0; h < 4; ++h) {  // rolled: h only appears in addresses
    float q[32];
#pragma unroll
    for (int i = 0; i < 32; ++i) {
      const float* wr = wq + (h * 32 + i) * 64;
      float a = 0.f;
#pragma unroll
      for (int c = 0; c < 64; ++c) a = fmaf(wr[c], xr[c], a);
      q[i] = a;
    }
    float m = q[0];
#pragma unroll
    for (int i = 1; i < 32; ++i) m = fmaxf(m, q[i]);
    float s = 0.f;
#pragma unroll
    for (int i = 0; i < 32; ++i) { q[i] = __expf(q[i] - m); s += q[i]; }
    const float inv = SCALEQ / s;
#pragma unroll
    for (int i = 0; i < 32; ++i) q[i] *= inv;

    // out_h[e] = sum_d ctx[h][e][d] * q[d]   (ctx reads are wave-uniform)
    float oh[32];
#pragma unroll
    for (int e = 0; e < 32; ++e) {
      const float* cr = &cl[(h * 32 + e) * 32];
      float a = 0.f;
#pragma unroll
      for (int d = 0; d < 32; ++d) a = fmaf(cr[d], q[d], a);
      oh[e] = a;
    }
    // y[o] += w_out[o][h*32+e] * out_h[e]
#pragma unroll
    for (int o = 0; o < 64; ++o) {
      const float* wr = wo + o * 128 + h * 32;
      float a = y0[o];
#pragma unroll
      for (int e = 0; e < 32; ++e) a = fmaf(wr[e], oh[e], a);
      y0[o] = a;
    }
  }
#pragma unroll
  for (int o = 0; o < 64; ++o)
    y[((size_t)(b * 64 + o) << 14) + p] = y0[o] + bo[o];
}

// ---------------- Kernel S: per-channel sum / sumsq ----------------
// grid = 2048 (each block: 8192 contiguous elements within one (b,o) slab)
__global__ __launch_bounds__(256) void kstats(const float* __restrict__ y,
                                              float* __restrict__ ssum,
                                              float* __restrict__ ssq) {
  const int t = threadIdx.x;
  const size_t base = (size_t)blockIdx.x * 8192;
  const int o = (blockIdx.x >> 1) & 63;
  float s = 0.f, q = 0.f;
#pragma unroll
  for (int it = 0; it < 8; ++it) {
    const float4 v = *(const float4*)&y[base + it * 1024 + t * 4];
    s += v.x + v.y + v.z + v.w;
    q += v.x * v.x + v.y * v.y + v.z * v.z + v.w * v.w;
  }
#pragma unroll
  for (int off = 32; off > 0; off >>= 1) {
    s += __shfl_down(s, off);
    q += __shfl_down(q, off);
  }
  __shared__ float ls[4], lq[4];
  if ((t & 63) == 0) { ls[t >> 6] = s; lq[t >> 6] = q; }
  __syncthreads();
  if (t == 0) {
    atomicAdd(&ssum[o], ls[0] + ls[1] + ls[2] + ls[3]);
    atomicAdd(&ssq[o], lq[0] + lq[1] + lq[2] + lq[3]);
  }
}

// ---------------- Kernel C: in-place BatchNorm apply ----------------
__global__ __launch_bounds__(256) void kbn(float* __restrict__ y,
                                           const float* __restrict__ ssum,
                                           const float* __restrict__ ssq,
                                           const float* __restrict__ gamma,
                                           const float* __restrict__ beta) {
  const int t = threadIdx.x;
  const size_t base = (size_t)blockIdx.x * 8192;
  const int o = (blockIdx.x >> 1) & 63;
  const float invn = 1.f / 262144.f;
  const float mean = ssum[o] * invn;
  const float var = ssq[o] * invn - mean * mean;
  const float g = gamma[o] * rsqrtf(var + EPSV);
  const float sh = beta[o] - mean * g;
#pragma unroll
  for (int it = 0; it < 8; ++it) {
    float4 v = *(float4*)&y[base + it * 1024 + t * 4];
    v.x = v.x * g + sh;
    v.y = v.y * g + sh;
    v.z = v.z * g + sh;
    v.w = v.w * g + sh;
    *(float4*)&y[base + it * 1024 + t * 4] = v;
  }
}

extern "C" void kernel_launch(void* const* d_in, const int* in_sizes, int n_in,
                              void* d_out, int out_size, void* d_ws, size_t ws_size,
                              hipStream_t stream) {
  (void)in_sizes; (void)n_in; (void)out_size; (void)ws_size;
  const float* x     = (const float*)d_in[0];
  const float* wq    = (const float*)d_in[1];
  const float* wo    = (const float*)d_in[2];
  const float* bo    = (const float*)d_in[3];
  const float* gamma = (const float*)d_in[4];
  const float* beta  = (const float*)d_in[5];
  float* out = (float*)d_out;
  float* ctxT = (float*)d_ws;               // 16*4096 floats
  float* ssum = ctxT + 16 * 4096;           // 64 floats
  float* ssq  = ssum + 64;                  // 64 floats

  hipMemsetAsync(d_ws, 0, (16 * 4096 + 128) * sizeof(float), stream);
  kctx<<<512, 256, 0, stream>>>(x, wq, ctxT);
  kout<<<1024, 256, 0, stream>>>(x, wq, wo, bo, ctxT, out);
  kstats<<<2048, 256, 0, stream>>>(out, ssum, ssq);
  kbn<<<2048, 256, 0, stream>>>(out, ssum, ssq, gamma, beta);
}

// Round 3
// 1121.521 us; speedup vs baseline: 1.6279x; 1.6279x over previous
//
#include <hip/hip_runtime.h>

typedef __attribute__((ext_vector_type(8))) short bf16x8;
typedef __attribute__((ext_vector_type(4))) float f32x4;

#define SCALEQ 0.17677669529663687f  // 32^-0.5
#define EPSV 1e-5f

__device__ inline unsigned short f2bf(float f) {
  unsigned int u = __float_as_uint(f);
  return (unsigned short)((u + 0x7FFFu + ((u >> 16) & 1u)) >> 16);
}
__device__ inline unsigned int pack2(float a, float b) {
  return (unsigned int)f2bf(a) | ((unsigned int)f2bf(b) << 16);
}

// =====================================================================
// kwconv: wqkv fp32 [384][64] -> wbf bf16 [384][64]. grid 24, block 256.
// (store-only punning; readers are other kernels)
// =====================================================================
__global__ __launch_bounds__(256) void kwconv(const float* __restrict__ wqkv,
                                              unsigned short* __restrict__ wbf) {
  const int i = blockIdx.x * 256 + threadIdx.x;  // 6144 threads * 4 elems
  const float4 v = *(const float4*)&wqkv[i * 4];
  *(uint2*)&wbf[i * 4] = make_uint2(pack2(v.x, v.y), pack2(v.z, v.w));
}

// =====================================================================
// ktr: x [b][c][p] fp32  ->  xsw [b][p][c] bf16, granule-swizzled:
//      slot gout of row p holds source granule gout ^ (p&7) (8 bf16/granule)
// grid 16*64=1024, block 256
// =====================================================================
__global__ __launch_bounds__(256) void ktr(const float* __restrict__ x,
                                           unsigned short* __restrict__ xsw) {
  __shared__ float xl[64][264];
  const int t = threadIdx.x;
  const int b = blockIdx.x >> 6;
  const int p0 = (blockIdx.x & 63) << 8;
#pragma unroll
  for (int i = 0; i < 16; ++i) {
    int s = i * 256 + t;            // 4096 float4 slots: c = s>>6, f4 = s&63
    int c = s >> 6, f4 = s & 63;
    float4 v = *(const float4*)&x[((size_t)(b * 64 + c) << 14) + p0 + f4 * 4];
    *(float4*)&xl[c][f4 * 4] = v;
  }
  __syncthreads();
#pragma unroll
  for (int i = 0; i < 8; ++i) {
    int a = i * 256 + t;            // 2048 granule slots: row = a>>3, gout = a&7
    int row = a >> 3, gout = a & 7;
    int gsrc = gout ^ (row & 7);
    unsigned int w0 = pack2(xl[gsrc * 8 + 0][row], xl[gsrc * 8 + 1][row]);
    unsigned int w1 = pack2(xl[gsrc * 8 + 2][row], xl[gsrc * 8 + 3][row]);
    unsigned int w2 = pack2(xl[gsrc * 8 + 4][row], xl[gsrc * 8 + 5][row]);
    unsigned int w3 = pack2(xl[gsrc * 8 + 6][row], xl[gsrc * 8 + 7][row]);
    size_t off = ((size_t)(b * 16384 + p0 + row) * 64) + gout * 8;
    *(uint4*)&xsw[off] = make_uint4(w0, w1, w2, w3);
  }
}

// =====================================================================
// kctx: per 128-position tile: KV = Wkv*X via MFMA, softmax(k over d),
//       stage fp32 to LDS, VALU 4x4 outer product -> ctx[b][h][d][e]
// grid 16*128=2048, block 256 (4 waves)
// =====================================================================
__global__ __launch_bounds__(256) void kctx(const unsigned short* __restrict__ xsw,
                                            const unsigned short* __restrict__ wbf,
                                            float* __restrict__ ctx) {
  __shared__ __align__(16) unsigned short xs[128 * 64];  // [p][c-granule-swz] 16KB
  __shared__ __align__(16) float kvl[128][68];           // [p][r] r:0-31 k, 32-63 v
  const int t = threadIdx.x;
  const int l = t & 63;
  const int w = t >> 6;
  const int b = blockIdx.x >> 7;
  const int p0 = (blockIdx.x & 127) << 7;
  const int lo16 = l & 15, hi4 = l >> 4;
  const int dg = l & 7, eg = (l >> 3) & 7;

  {  // stage xs: linear 16KB copy (swizzle pre-baked in global layout)
    const uint4* src = (const uint4*)&xsw[(size_t)(b * 16384 + p0) * 64];
    uint4* dst = (uint4*)xs;
#pragma unroll
    for (int i = 0; i < 4; ++i) dst[i * 256 + t] = src[i * 256 + t];
  }
  __syncthreads();

  for (int h = 0; h < 4; ++h) {
    // ---- A-fragments (direct bf16 global loads, load-only, 16B aligned):
    //      k rows 128+h*32.. (Mt 0,1), v rows 256+h*32.. (Mt 2,3)
    bf16x8 afr[4][2];
#pragma unroll
    for (int Mt = 0; Mt < 4; ++Mt) {
      int row = (Mt < 2) ? (128 + h * 32 + Mt * 16 + lo16)
                         : (256 + h * 32 + (Mt - 2) * 16 + lo16);
#pragma unroll
      for (int Ks = 0; Ks < 2; ++Ks)
        afr[Mt][Ks] = *(const bf16x8*)&wbf[row * 64 + Ks * 32 + (hi4 << 3)];
    }
    __syncthreads();  // prev head's reduction reads of kvl done

    // ---- GEMM1 over this wave's 2 N-tiles + softmax(k) + stage to LDS
#pragma unroll
    for (int nt = 0; nt < 2; ++nt) {
      const int Nt = w * 2 + nt;
      const int p = Nt * 16 + lo16;
      f32x4 acc[4];
#pragma unroll
      for (int Mt = 0; Mt < 4; ++Mt) acc[Mt] = (f32x4){0.f, 0.f, 0.f, 0.f};
#pragma unroll
      for (int Ks = 0; Ks < 2; ++Ks) {
        int g = Ks * 4 + hi4;
        bf16x8 bfr = *(const bf16x8*)&xs[p * 64 + ((g ^ (p & 7)) << 3)];
#pragma unroll
        for (int Mt = 0; Mt < 4; ++Mt)
          acc[Mt] = __builtin_amdgcn_mfma_f32_16x16x32_bf16(afr[Mt][Ks], bfr,
                                                            acc[Mt], 0, 0, 0);
      }
      // softmax over the 32 k-features (acc[0],acc[1]) for this position
      float m = acc[0][0];
#pragma unroll
      for (int r = 1; r < 4; ++r) m = fmaxf(m, acc[0][r]);
#pragma unroll
      for (int r = 0; r < 4; ++r) m = fmaxf(m, acc[1][r]);
      m = fmaxf(m, __shfl_xor(m, 16));
      m = fmaxf(m, __shfl_xor(m, 32));
      float s = 0.f;
#pragma unroll
      for (int Mt = 0; Mt < 2; ++Mt)
#pragma unroll
        for (int r = 0; r < 4; ++r) {
          acc[Mt][r] = __expf(acc[Mt][r] - m);
          s += acc[Mt][r];
        }
      s += __shfl_xor(s, 16);
      s += __shfl_xor(s, 32);
      const float inv = 1.f / s;
#pragma unroll
      for (int Mt = 0; Mt < 4; ++Mt) {
        float sc = (Mt < 2) ? inv : 1.f;
        int r0 = (Mt < 2) ? (Mt * 16 + hi4 * 4) : (32 + (Mt - 2) * 16 + hi4 * 4);
        *(float2*)&kvl[p][r0] = make_float2(acc[Mt][0] * sc, acc[Mt][1] * sc);
        *(float2*)&kvl[p][r0 + 2] = make_float2(acc[Mt][2] * sc, acc[Mt][3] * sc);
      }
    }
    __syncthreads();

    // ---- VALU outer product: ctx[d][e] += sum_p k[p][d]*v[p][e]
    float ao[4][4];
#pragma unroll
    for (int i = 0; i < 4; ++i)
#pragma unroll
      for (int j = 0; j < 4; ++j) ao[i][j] = 0.f;
    for (int ks = 0; ks < 32; ++ks) {
      int p = w * 32 + ks;
      float4 kv = *(const float4*)&kvl[p][dg * 4];       // broadcast reads
      float4 vv = *(const float4*)&kvl[p][32 + eg * 4];
      float ka[4] = {kv.x, kv.y, kv.z, kv.w};
      float va[4] = {vv.x, vv.y, vv.z, vv.w};
#pragma unroll
      for (int i = 0; i < 4; ++i)
#pragma unroll
        for (int j = 0; j < 4; ++j) ao[i][j] = fmaf(ka[i], va[j], ao[i][j]);
    }
    __syncthreads();  // all outer-product reads done before kvl reuse

    // ---- block reduction across the 4 waves, then atomics
    float* red = &kvl[0][0];  // reuse: 256*17 = 4352 <= 8704 floats
#pragma unroll
    for (int i = 0; i < 16; ++i)
      red[(w * 64 + l) * 17 + i] = ao[i >> 2][i & 3];
    __syncthreads();
    if (w == 0) {
#pragma unroll
      for (int i = 0; i < 16; ++i) {
        float s = red[l * 17 + i] + red[(64 + l) * 17 + i] +
                  red[(128 + l) * 17 + i] + red[(192 + l) * 17 + i];
        int d = dg * 4 + (i >> 2), e = eg * 4 + (i & 3);
        atomicAdd(&ctx[(size_t)((b * 4 + h) * 32 + d) * 32 + e], s);
      }
    }
  }
}

// =====================================================================
// kweff: Weff[b][o][h*32+d] = SCALEQ * sum_e Wo[o][h*32+e] * ctx[b][h][d][e]
//        emitted directly as bf16. grid 16, block 256
// =====================================================================
__global__ __launch_bounds__(256) void kweff(const float* __restrict__ ctx,
                                             const float* __restrict__ wo,
                                             unsigned short* __restrict__ weffbf) {
  __shared__ float ctxl[4 * 1064];  // [h][d][33] (+8 pad per h)
  const int t = threadIdx.x;
  const int b = blockIdx.x;
#pragma unroll
  for (int i = 0; i < 16; ++i) {
    int idx = i * 256 + t;
    int h = idx >> 10, d = (idx >> 5) & 31, e = idx & 31;
    ctxl[h * 1064 + d * 33 + e] = ctx[(size_t)(b * 4 + h) * 1024 + d * 32 + e];
  }
  __syncthreads();
  const int o = t >> 2, h = t & 3;
  float wr[32];
#pragma unroll
  for (int e4 = 0; e4 < 8; ++e4) {
    float4 v = *(const float4*)&wo[o * 128 + h * 32 + e4 * 4];
    wr[e4 * 4] = v.x; wr[e4 * 4 + 1] = v.y;
    wr[e4 * 4 + 2] = v.z; wr[e4 * 4 + 3] = v.w;
  }
  for (int d = 0; d < 32; ++d) {
    float s = 0.f;
#pragma unroll
    for (int e = 0; e < 32; ++e) s = fmaf(wr[e], ctxl[h * 1064 + d * 33 + e], s);
    weffbf[(size_t)b * 8192 + o * 128 + h * 32 + d] = f2bf(s * SCALEQ);
  }
}

// =====================================================================
// kout: q = softmax(Wq*X) via MFMA; y = Weff*qs + bias via MFMA;
//       fused BN-statistics. grid 16*128=2048, block 256 (4 waves)
// =====================================================================
__global__ __launch_bounds__(256) void kout(const unsigned short* __restrict__ xsw,
                                            const unsigned short* __restrict__ wbf,
                                            const unsigned short* __restrict__ weffbf,
                                            const float* __restrict__ bo,
                                            float* __restrict__ y,
                                            float* __restrict__ ssum,
                                            float* __restrict__ ssq) {
  __shared__ __align__(16) unsigned short xs[128 * 64];    // 16KB
  __shared__ __align__(16) unsigned short qsl[128 * 128];  // 32KB [p][hd] swz g^=(p&15)
  const int t = threadIdx.x;
  const int l = t & 63;
  const int w = t >> 6;
  const int b = blockIdx.x >> 7;
  const int p0 = (blockIdx.x & 127) << 7;
  const int lo16 = l & 15, hi4 = l >> 4;
  const unsigned short* web = weffbf + ((size_t)b << 13);

  {  // stage xs (linear copy; swizzle pre-baked in global layout)
    const uint4* src = (const uint4*)&xsw[(size_t)(b * 16384 + p0) * 64];
    uint4* dst = (uint4*)xs;
#pragma unroll
    for (int i = 0; i < 4; ++i) dst[i * 256 + t] = src[i * 256 + t];
  }
  __syncthreads();

  // ---- GEMM-Q: wave w = head w (q rows w*32..w*32+31)
  {
    bf16x8 aq[2][2];
#pragma unroll
    for (int Mt = 0; Mt < 2; ++Mt) {
      int row = w * 32 + Mt * 16 + lo16;
#pragma unroll
      for (int Ks = 0; Ks < 2; ++Ks)
        aq[Mt][Ks] = *(const bf16x8*)&wbf[row * 64 + Ks * 32 + (hi4 << 3)];
    }
#pragma unroll
    for (int Nt = 0; Nt < 8; ++Nt) {
      const int p = Nt * 16 + lo16;
      f32x4 acc[2];
      acc[0] = (f32x4){0.f, 0.f, 0.f, 0.f};
      acc[1] = (f32x4){0.f, 0.f, 0.f, 0.f};
#pragma unroll
      for (int Ks = 0; Ks < 2; ++Ks) {
        int g = Ks * 4 + hi4;
        bf16x8 bfr = *(const bf16x8*)&xs[p * 64 + ((g ^ (p & 7)) << 3)];
#pragma unroll
        for (int Mt = 0; Mt < 2; ++Mt)
          acc[Mt] = __builtin_amdgcn_mfma_f32_16x16x32_bf16(aq[Mt][Ks], bfr,
                                                            acc[Mt], 0, 0, 0);
      }
      float m = acc[0][0];
#pragma unroll
      for (int r = 1; r < 4; ++r) m = fmaxf(m, acc[0][r]);
#pragma unroll
      for (int r = 0; r < 4; ++r) m = fmaxf(m, acc[1][r]);
      m = fmaxf(m, __shfl_xor(m, 16));
      m = fmaxf(m, __shfl_xor(m, 32));
      float s = 0.f;
#pragma unroll
      for (int Mt = 0; Mt < 2; ++Mt)
#pragma unroll
        for (int r = 0; r < 4; ++r) {
          acc[Mt][r] = __expf(acc[Mt][r] - m);
          s += acc[Mt][r];
        }
      s += __shfl_xor(s, 16);
      s += __shfl_xor(s, 32);
      const float inv = 1.f / s;
#pragma unroll
      for (int Mt = 0; Mt < 2; ++Mt) {
#pragma unroll
        for (int pr = 0; pr < 2; ++pr) {
          int hd = w * 32 + Mt * 16 + hi4 * 4 + pr * 2;
          int g = hd >> 3;
          int col = ((g ^ (p & 15)) << 3) | (hd & 7);
          *(unsigned int*)&qsl[p * 128 + col] =
              pack2(acc[Mt][pr * 2] * inv, acc[Mt][pr * 2 + 1] * inv);
        }
      }
    }
  }
  __syncthreads();

  // ---- GEMM-Y: y[o][p] = sum_hd Weff[o][hd]*qs[hd][p]; wave w: Nt {2w,2w+1}
  f32x4 accY[2][4];
#pragma unroll
  for (int nt = 0; nt < 2; ++nt)
#pragma unroll
    for (int Mt = 0; Mt < 4; ++Mt) accY[nt][Mt] = (f32x4){0.f, 0.f, 0.f, 0.f};
#pragma unroll
  for (int nt = 0; nt < 2; ++nt) {
    const int p = (w * 2 + nt) * 16 + lo16;
#pragma unroll
    for (int Ks = 0; Ks < 4; ++Ks) {
      int g = Ks * 4 + hi4;
      bf16x8 bq = *(const bf16x8*)&qsl[p * 128 + ((g ^ (p & 15)) << 3)];
#pragma unroll
      for (int Mt = 0; Mt < 4; ++Mt) {
        int o = Mt * 16 + lo16;
        bf16x8 aw = *(const bf16x8*)&web[o * 128 + (g << 3)];
        accY[nt][Mt] = __builtin_amdgcn_mfma_f32_16x16x32_bf16(aw, bq,
                                                               accY[nt][Mt], 0, 0, 0);
      }
    }
  }

  // ---- epilogue: bias, store, fused BN partial stats
  float sacc[16], qacc[16];
#pragma unroll
  for (int i = 0; i < 16; ++i) { sacc[i] = 0.f; qacc[i] = 0.f; }
#pragma unroll
  for (int nt = 0; nt < 2; ++nt) {
    const int p = p0 + (w * 2 + nt) * 16 + lo16;
#pragma unroll
    for (int Mt = 0; Mt < 4; ++Mt) {
#pragma unroll
      for (int r = 0; r < 4; ++r) {
        int o = Mt * 16 + hi4 * 4 + r;
        float val = accY[nt][Mt][r] + bo[o];
        y[((size_t)(b * 64 + o) << 14) + p] = val;
        sacc[Mt * 4 + r] += val;
        qacc[Mt * 4 + r] += val * val;
      }
    }
  }
#pragma unroll
  for (int off = 1; off < 16; off <<= 1) {
#pragma unroll
    for (int i = 0; i < 16; ++i) {
      sacc[i] += __shfl_xor(sacc[i], off);
      qacc[i] += __shfl_xor(qacc[i], off);
    }
  }
  if (lo16 == 0) {
#pragma unroll
    for (int i = 0; i < 16; ++i) {
      int o = (i >> 2) * 16 + hi4 * 4 + (i & 3);
      atomicAdd(&ssum[o], sacc[i]);
      atomicAdd(&ssq[o], qacc[i]);
    }
  }
}

// =====================================================================
// kbn: in-place BatchNorm apply (grid 2048, block 256)
// =====================================================================
__global__ __launch_bounds__(256) void kbn(float* __restrict__ y,
                                           const float* __restrict__ ssum,
                                           const float* __restrict__ ssq,
                                           const float* __restrict__ gamma,
                                           const float* __restrict__ beta) {
  const int t = threadIdx.x;
  const size_t base = (size_t)blockIdx.x * 8192;
  const int o = (blockIdx.x >> 1) & 63;
  const float invn = 1.f / 262144.f;
  const float mean = ssum[o] * invn;
  const float var = ssq[o] * invn - mean * mean;
  const float g = gamma[o] * rsqrtf(var + EPSV);
  const float sh = beta[o] - mean * g;
#pragma unroll
  for (int it = 0; it < 8; ++it) {
    float4 v = *(float4*)&y[base + it * 1024 + t * 4];
    v.x = v.x * g + sh;
    v.y = v.y * g + sh;
    v.z = v.z * g + sh;
    v.w = v.w * g + sh;
    *(float4*)&y[base + it * 1024 + t * 4] = v;
  }
}

// =====================================================================
// ============ Fallback path (round-0, known-correct) ==================
// =====================================================================
__global__ __launch_bounds__(256) void kctx0(const float* __restrict__ x,
                                             const float* __restrict__ wq,
                                             float* __restrict__ ctxT) {
  __shared__ float kT[32 * 256];
  __shared__ float vT[32 * 256];
  const int t = threadIdx.x;
  const int b = blockIdx.x >> 5;
  const int tile = blockIdx.x & 31;
  const int d0 = (t & 15) << 1;
  const int e0 = (t >> 4) << 1;
  float acc[4][2][2];
#pragma unroll
  for (int h = 0; h < 4; ++h)
#pragma unroll
    for (int i = 0; i < 2; ++i)
#pragma unroll
      for (int j = 0; j < 2; ++j) acc[h][i][j] = 0.f;
  for (int chunk = 0; chunk < 2; ++chunk) {
    const int p = (tile << 9) + (chunk << 8) + t;
    float xr[64];
#pragma unroll
    for (int c = 0; c < 64; ++c) xr[c] = x[((size_t)(b * 64 + c) << 14) + p];
#pragma unroll
    for (int h = 0; h < 4; ++h) {
      float kk[32];
#pragma unroll
      for (int i = 0; i < 32; ++i) {
        const float* wr = wq + (128 + h * 32 + i) * 64;
        float a = 0.f;
#pragma unroll
        for (int c = 0; c < 64; ++c) a = fmaf(wr[c], xr[c], a);
        kk[i] = a;
      }
      float m = kk[0];
#pragma unroll
      for (int i = 1; i < 32; ++i) m = fmaxf(m, kk[i]);
      float s = 0.f;
#pragma unroll
      for (int i = 0; i < 32; ++i) { kk[i] = __expf(kk[i] - m); s += kk[i]; }
      const float inv = 1.f / s;
      float vv[32];
#pragma unroll
      for (int i = 0; i < 32; ++i) {
        const float* wr = wq + (256 + h * 32 + i) * 64;
        float a = 0.f;
#pragma unroll
        for (int c = 0; c < 64; ++c) a = fmaf(wr[c], xr[c], a);
        vv[i] = a;
      }
      __syncthreads();
#pragma unroll
      for (int i = 0; i < 32; ++i) kT[i * 256 + (t ^ (2 * i))] = kk[i] * inv;
#pragma unroll
      for (int i = 0; i < 32; ++i) vT[i * 256 + t] = vv[i];
      __syncthreads();
#pragma unroll 2
      for (int p2 = 0; p2 < 256; p2 += 2) {
        const float2 k0 = *(const float2*)&kT[d0 * 256 + (p2 ^ (2 * d0))];
        const float2 k1 = *(const float2*)&kT[(d0 + 1) * 256 + (p2 ^ (2 * (d0 + 1)))];
        const float2 v0 = *(const float2*)&vT[e0 * 256 + p2];
        const float2 v1 = *(const float2*)&vT[(e0 + 1) * 256 + p2];
        acc[h][0][0] += k0.x * v0.x + k0.y * v0.y;
        acc[h][0][1] += k0.x * v1.x + k0.y * v1.y;
        acc[h][1][0] += k1.x * v0.x + k1.y * v0.y;
        acc[h][1][1] += k1.x * v1.x + k1.y * v1.y;
      }
    }
  }
#pragma unroll
  for (int h = 0; h < 4; ++h)
#pragma unroll
    for (int i = 0; i < 2; ++i)
#pragma unroll
      for (int j = 0; j < 2; ++j)
        atomicAdd(&ctxT[(((b * 4 + h) * 32) + (e0 + j)) * 32 + (d0 + i)],
                  acc[h][i][j]);
}

__global__ __launch_bounds__(256) void kout0(const float* __restrict__ x,
                                             const float* __restrict__ wq,
                                             const float* __restrict__ wo,
                                             const float* __restrict__ bo,
                                             const float* __restrict__ ctxT,
                                             float* __restrict__ y) {
  __shared__ float cl[4096];
  const int t = threadIdx.x;
  const int b = blockIdx.x >> 6;
  const int tile = blockIdx.x & 63;
  const int p = (tile << 8) + t;
#pragma unroll
  for (int i = 0; i < 16; ++i) cl[i * 256 + t] = ctxT[(b << 12) + i * 256 + t];
  __syncthreads();
  float xr[64];
#pragma unroll
  for (int c = 0; c < 64; ++c) xr[c] = x[((size_t)(b * 64 + c) << 14) + p];
  float y0[64];
#pragma unroll
  for (int o = 0; o < 64; ++o) y0[o] = 0.f;
  for (int h = 0; h < 4; ++h) {
    float q[32];
#pragma unroll
    for (int i = 0; i < 32; ++i) {
      const float* wr = wq + (h * 32 + i) * 64;
      float a = 0.f;
#pragma unroll
      for (int c = 0; c < 64; ++c) a = fmaf(wr[c], xr[c], a);
      q[i] = a;
    }
    float m = q[0];
#pragma unroll
    for (int i = 1; i < 32; ++i) m = fmaxf(m, q[i]);
    float s = 0.f;
#pragma unroll
    for (int i = 0; i < 32; ++i) { q[i] = __expf(q[i] - m); s += q[i]; }
    const float inv = SCALEQ / s;
#pragma unroll
    for (int i = 0; i < 32; ++i) q[i] *= inv;
    float oh[32];
#pragma unroll
    for (int e = 0; e < 32; ++e) {
      const float* cr = &cl[(h * 32 + e) * 32];
      float a = 0.f;
#pragma unroll
      for (int d = 0; d < 32; ++d) a = fmaf(cr[d], q[d], a);
      oh[e] = a;
    }
#pragma unroll
    for (int o = 0; o < 64; ++o) {
      const float* wr = wo + o * 128 + h * 32;
      float a = y0[o];
#pragma unroll
      for (int e = 0; e < 32; ++e) a = fmaf(wr[e], oh[e], a);
      y0[o] = a;
    }
  }
#pragma unroll
  for (int o = 0; o < 64; ++o)
    y[((size_t)(b * 64 + o) << 14) + p] = y0[o] + bo[o];
}

__global__ __launch_bounds__(256) void kstats0(const float* __restrict__ y,
                                               float* __restrict__ ssum,
                                               float* __restrict__ ssq) {
  const int t = threadIdx.x;
  const size_t base = (size_t)blockIdx.x * 8192;
  const int o = (blockIdx.x >> 1) & 63;
  float s = 0.f, q = 0.f;
#pragma unroll
  for (int it = 0; it < 8; ++it) {
    const float4 v = *(const float4*)&y[base + it * 1024 + t * 4];
    s += v.x + v.y + v.z + v.w;
    q += v.x * v.x + v.y * v.y + v.z * v.z + v.w * v.w;
  }
#pragma unroll
  for (int off = 32; off > 0; off >>= 1) {
    s += __shfl_down(s, off);
    q += __shfl_down(q, off);
  }
  __shared__ float ls[4], lq[4];
  if ((t & 63) == 0) { ls[t >> 6] = s; lq[t >> 6] = q; }
  __syncthreads();
  if (t == 0) {
    atomicAdd(&ssum[o], ls[0] + ls[1] + ls[2] + ls[3]);
    atomicAdd(&ssq[o], lq[0] + lq[1] + lq[2] + lq[3]);
  }
}

// =====================================================================
extern "C" void kernel_launch(void* const* d_in, const int* in_sizes, int n_in,
                              void* d_out, int out_size, void* d_ws, size_t ws_size,
                              hipStream_t stream) {
  (void)in_sizes; (void)n_in; (void)out_size;
  const float* x     = (const float*)d_in[0];
  const float* wq    = (const float*)d_in[1];
  const float* wo    = (const float*)d_in[2];
  const float* bo    = (const float*)d_in[3];
  const float* gamma = (const float*)d_in[4];
  const float* beta  = (const float*)d_in[5];
  float* out = (float*)d_out;

  // workspace layout (bytes):
  // ctx    @ 0        : 262144  (65536 f32)
  // ssum   @ 262144   : 256     (64 f32)
  // ssq    @ 262400   : 256     (64 f32)
  // weffbf @ 262656   : 262144  (16*64*128 bf16)
  // wbf    @ 524800   : 49152   (384*64 bf16)
  // xsw    @ 573952   : 33554432 (16*16384*64 bf16)
  float* ctx  = (float*)d_ws;
  float* ssum = (float*)((char*)d_ws + 262144);
  float* ssq  = (float*)((char*)d_ws + 262400);
  unsigned short* weffbf = (unsigned short*)((char*)d_ws + 262656);
  unsigned short* wbf    = (unsigned short*)((char*)d_ws + 524800);
  unsigned short* xsw    = (unsigned short*)((char*)d_ws + 573952);
  const size_t need = 573952 + (size_t)16 * 16384 * 64 * 2;

  hipMemsetAsync(d_ws, 0, 262656, stream);  // ctx + ssum + ssq
  if (ws_size >= need) {
    kwconv<<<24, 256, 0, stream>>>(wq, wbf);
    ktr<<<1024, 256, 0, stream>>>(x, xsw);
    kctx<<<2048, 256, 0, stream>>>(xsw, wbf, ctx);
    kweff<<<16, 256, 0, stream>>>(ctx, wo, weffbf);
    kout<<<2048, 256, 0, stream>>>(xsw, wbf, weffbf, bo, out, ssum, ssq);
    kbn<<<2048, 256, 0, stream>>>(out, ssum, ssq, gamma, beta);
  } else {
    kctx0<<<512, 256, 0, stream>>>(x, wq, ctx);
    kout0<<<1024, 256, 0, stream>>>(x, wq, wo, bo, ctx, out);
    kstats0<<<2048, 256, 0, stream>>>(out, ssum, ssq);
    kbn<<<2048, 256, 0, stream>>>(out, ssum, ssq, gamma, beta);
  }
}

// Round 5
// 362.806 us; speedup vs baseline: 5.0322x; 3.0912x over previous
//
#include <hip/hip_runtime.h>

typedef __attribute__((ext_vector_type(8))) short bf16x8;
typedef __attribute__((ext_vector_type(4))) float f32x4;

#define SCALEQ 0.17677669529663687f  // 32^-0.5
#define EPSV 1e-5f

__device__ inline unsigned short f2bf(float f) {
  unsigned int u = __float_as_uint(f);
  return (unsigned short)((u + 0x7FFFu + ((u >> 16) & 1u)) >> 16);
}
__device__ inline unsigned int pack2(float a, float b) {
  return (unsigned int)f2bf(a) | ((unsigned int)f2bf(b) << 16);
}

// =====================================================================
// kwconv: wqkv fp32 [384][64] -> wbf bf16 [384][64]. grid 24, block 256.
// =====================================================================
__global__ __launch_bounds__(256) void kwconv(const float* __restrict__ wqkv,
                                              unsigned short* __restrict__ wbf) {
  const int i = blockIdx.x * 256 + threadIdx.x;  // 6144 threads * 4 elems
  const float4 v = *(const float4*)&wqkv[i * 4];
  *(uint2*)&wbf[i * 4] = make_uint2(pack2(v.x, v.y), pack2(v.z, v.w));
}

// =====================================================================
// ktr: x [b][c][p] fp32  ->  xsw [b][p][c] bf16, granule-swizzled:
//      slot gout of row p holds source granule gout ^ (p&7) (8 bf16/granule)
// grid 16*64=1024, block 256. LDS transpose buffer XOR-swizzled:
//      physical col = col ^ ((c>>3)<<2)  (conflict-free stores, 2-way reads)
// =====================================================================
__global__ __launch_bounds__(256) void ktr(const float* __restrict__ x,
                                           unsigned short* __restrict__ xsw) {
  __shared__ float xl[64][256];
  const int t = threadIdx.x;
  const int b = blockIdx.x >> 6;
  const int p0 = (blockIdx.x & 63) << 8;
#pragma unroll
  for (int i = 0; i < 16; ++i) {
    int s = i * 256 + t;            // 4096 float4 slots: c = s>>6, f4 = s&63
    int c = s >> 6, f4 = s & 63;
    float4 v = *(const float4*)&x[((size_t)(b * 64 + c) << 14) + p0 + f4 * 4];
    *(float4*)&xl[c][(f4 * 4) ^ ((c >> 3) << 2)] = v;
  }
  __syncthreads();
#pragma unroll
  for (int i = 0; i < 8; ++i) {
    int a = i * 256 + t;            // 2048 granule slots: row = a>>3, gout = a&7
    int row = a >> 3, gout = a & 7;
    int gsrc = gout ^ (row & 7);
    int col = row ^ (gsrc << 2);    // same swizzle on read side
    unsigned int w0 = pack2(xl[gsrc * 8 + 0][col], xl[gsrc * 8 + 1][col]);
    unsigned int w1 = pack2(xl[gsrc * 8 + 2][col], xl[gsrc * 8 + 3][col]);
    unsigned int w2 = pack2(xl[gsrc * 8 + 4][col], xl[gsrc * 8 + 5][col]);
    unsigned int w3 = pack2(xl[gsrc * 8 + 6][col], xl[gsrc * 8 + 7][col]);
    size_t off = ((size_t)(b * 16384 + p0 + row) * 64) + gout * 8;
    *(uint4*)&xsw[off] = make_uint4(w0, w1, w2, w3);
  }
}

// =====================================================================
// kctx: per 128-position tile: KV = Wkv*X via MFMA, softmax(k over d),
//       stage fp32 to LDS, VALU 4x4 outer product -> ctx[b][h][d][e]
// grid 16*128=2048, block 256 (4 waves)
// =====================================================================
__global__ __launch_bounds__(256) void kctx(const unsigned short* __restrict__ xsw,
                                            const unsigned short* __restrict__ wbf,
                                            float* __restrict__ ctx) {
  __shared__ __align__(16) unsigned short xs[128 * 64];  // [p][c-granule-swz] 16KB
  __shared__ __align__(16) float kvl[128][68];           // [p][r] r:0-31 k, 32-63 v
  const int t = threadIdx.x;
  const int l = t & 63;
  const int w = t >> 6;
  const int b = blockIdx.x >> 7;
  const int p0 = (blockIdx.x & 127) << 7;
  const int lo16 = l & 15, hi4 = l >> 4;
  const int dg = l & 7, eg = (l >> 3) & 7;

  {  // stage xs: linear 16KB copy (swizzle pre-baked in global layout)
    const uint4* src = (const uint4*)&xsw[(size_t)(b * 16384 + p0) * 64];
    uint4* dst = (uint4*)xs;
#pragma unroll
    for (int i = 0; i < 4; ++i) dst[i * 256 + t] = src[i * 256 + t];
  }
  __syncthreads();

  for (int h = 0; h < 4; ++h) {
    // ---- A-fragments (direct bf16 global loads, load-only, 16B aligned):
    //      k rows 128+h*32.. (Mt 0,1), v rows 256+h*32.. (Mt 2,3)
    bf16x8 afr[4][2];
#pragma unroll
    for (int Mt = 0; Mt < 4; ++Mt) {
      int row = (Mt < 2) ? (128 + h * 32 + Mt * 16 + lo16)
                         : (256 + h * 32 + (Mt - 2) * 16 + lo16);
#pragma unroll
      for (int Ks = 0; Ks < 2; ++Ks)
        afr[Mt][Ks] = *(const bf16x8*)&wbf[row * 64 + Ks * 32 + (hi4 << 3)];
    }
    __syncthreads();  // prev head's reduction reads of kvl done

    // ---- GEMM1 over this wave's 2 N-tiles + softmax(k) + stage to LDS
#pragma unroll
    for (int nt = 0; nt < 2; ++nt) {
      const int Nt = w * 2 + nt;
      const int p = Nt * 16 + lo16;
      f32x4 acc[4];
#pragma unroll
      for (int Mt = 0; Mt < 4; ++Mt) acc[Mt] = (f32x4){0.f, 0.f, 0.f, 0.f};
#pragma unroll
      for (int Ks = 0; Ks < 2; ++Ks) {
        int g = Ks * 4 + hi4;
        bf16x8 bfr = *(const bf16x8*)&xs[p * 64 + ((g ^ (p & 7)) << 3)];
#pragma unroll
        for (int Mt = 0; Mt < 4; ++Mt)
          acc[Mt] = __builtin_amdgcn_mfma_f32_16x16x32_bf16(afr[Mt][Ks], bfr,
                                                            acc[Mt], 0, 0, 0);
      }
      // softmax over the 32 k-features (acc[0],acc[1]) for this position
      float m = acc[0][0];
#pragma unroll
      for (int r = 1; r < 4; ++r) m = fmaxf(m, acc[0][r]);
#pragma unroll
      for (int r = 0; r < 4; ++r) m = fmaxf(m, acc[1][r]);
      m = fmaxf(m, __shfl_xor(m, 16));
      m = fmaxf(m, __shfl_xor(m, 32));
      float s = 0.f;
#pragma unroll
      for (int Mt = 0; Mt < 2; ++Mt)
#pragma unroll
        for (int r = 0; r < 4; ++r) {
          acc[Mt][r] = __expf(acc[Mt][r] - m);
          s += acc[Mt][r];
        }
      s += __shfl_xor(s, 16);
      s += __shfl_xor(s, 32);
      const float inv = 1.f / s;
#pragma unroll
      for (int Mt = 0; Mt < 4; ++Mt) {
        float sc = (Mt < 2) ? inv : 1.f;
        int r0 = (Mt < 2) ? (Mt * 16 + hi4 * 4) : (32 + (Mt - 2) * 16 + hi4 * 4);
        *(float2*)&kvl[p][r0] = make_float2(acc[Mt][0] * sc, acc[Mt][1] * sc);
        *(float2*)&kvl[p][r0 + 2] = make_float2(acc[Mt][2] * sc, acc[Mt][3] * sc);
      }
    }
    __syncthreads();

    // ---- VALU outer product: ctx[d][e] += sum_p k[p][d]*v[p][e]
    float ao[4][4];
#pragma unroll
    for (int i = 0; i < 4; ++i)
#pragma unroll
      for (int j = 0; j < 4; ++j) ao[i][j] = 0.f;
    for (int ks = 0; ks < 32; ++ks) {
      int p = w * 32 + ks;
      float4 kv = *(const float4*)&kvl[p][dg * 4];       // broadcast reads
      float4 vv = *(const float4*)&kvl[p][32 + eg * 4];
      float ka[4] = {kv.x, kv.y, kv.z, kv.w};
      float va[4] = {vv.x, vv.y, vv.z, vv.w};
#pragma unroll
      for (int i = 0; i < 4; ++i)
#pragma unroll
        for (int j = 0; j < 4; ++j) ao[i][j] = fmaf(ka[i], va[j], ao[i][j]);
    }
    __syncthreads();  // all outer-product reads done before kvl reuse

    // ---- block reduction across the 4 waves, then atomics
    float* red = &kvl[0][0];  // reuse: 256*17 = 4352 <= 8704 floats
#pragma unroll
    for (int i = 0; i < 16; ++i)
      red[(w * 64 + l) * 17 + i] = ao[i >> 2][i & 3];
    __syncthreads();
    if (w == 0) {
#pragma unroll
      for (int i = 0; i < 16; ++i) {
        float s = red[l * 17 + i] + red[(64 + l) * 17 + i] +
                  red[(128 + l) * 17 + i] + red[(192 + l) * 17 + i];
        int d = dg * 4 + (i >> 2), e = eg * 4 + (i & 3);
        atomicAdd(&ctx[(size_t)((b * 4 + h) * 32 + d) * 32 + e], s);
      }
    }
  }
}

// =====================================================================
// kweff: Weff[b][o][h*32+d] = SCALEQ * sum_e Wo[o][h*32+e] * ctx[b][h][d][e]
//        emitted directly as bf16. grid 16, block 256
// =====================================================================
__global__ __launch_bounds__(256) void kweff(const float* __restrict__ ctx,
                                             const float* __restrict__ wo,
                                             unsigned short* __restrict__ weffbf) {
  __shared__ float ctxl[4 * 1064];  // [h][d][33] (+8 pad per h)
  const int t = threadIdx.x;
  const int b = blockIdx.x;
#pragma unroll
  for (int i = 0; i < 16; ++i) {
    int idx = i * 256 + t;
    int h = idx >> 10, d = (idx >> 5) & 31, e = idx & 31;
    ctxl[h * 1064 + d * 33 + e] = ctx[(size_t)(b * 4 + h) * 1024 + d * 32 + e];
  }
  __syncthreads();
  const int o = t >> 2, h = t & 3;
  float wr[32];
#pragma unroll
  for (int e4 = 0; e4 < 8; ++e4) {
    float4 v = *(const float4*)&wo[o * 128 + h * 32 + e4 * 4];
    wr[e4 * 4] = v.x; wr[e4 * 4 + 1] = v.y;
    wr[e4 * 4 + 2] = v.z; wr[e4 * 4 + 3] = v.w;
  }
  for (int d = 0; d < 32; ++d) {
    float s = 0.f;
#pragma unroll
    for (int e = 0; e < 32; ++e) s = fmaf(wr[e], ctxl[h * 1064 + d * 33 + e], s);
    weffbf[(size_t)b * 8192 + o * 128 + h * 32 + d] = f2bf(s * SCALEQ);
  }
}

// =====================================================================
// kout: q = softmax(Wq*X) via MFMA; y = Weff*qs + bias via MFMA;
//       per-block BN partials (NO global atomics). grid 2048, block 256
// =====================================================================
__global__ __launch_bounds__(256) void kout(const unsigned short* __restrict__ xsw,
                                            const unsigned short* __restrict__ wbf,
                                            const unsigned short* __restrict__ weffbf,
                                            const float* __restrict__ bo,
                                            float* __restrict__ y,
                                            float* __restrict__ pstats) {
  __shared__ __align__(16) unsigned short xs[128 * 64];    // 16KB
  __shared__ __align__(16) unsigned short qsl[128 * 128];  // 32KB [p][hd] swz g^=(p&15)
  const int t = threadIdx.x;
  const int l = t & 63;
  const int w = t >> 6;
  const int b = blockIdx.x >> 7;
  const int p0 = (blockIdx.x & 127) << 7;
  const int lo16 = l & 15, hi4 = l >> 4;
  const unsigned short* web = weffbf + ((size_t)b << 13);

  {  // stage xs (linear copy; swizzle pre-baked in global layout)
    const uint4* src = (const uint4*)&xsw[(size_t)(b * 16384 + p0) * 64];
    uint4* dst = (uint4*)xs;
#pragma unroll
    for (int i = 0; i < 4; ++i) dst[i * 256 + t] = src[i * 256 + t];
  }
  __syncthreads();

  // ---- GEMM-Q: wave w = head w (q rows w*32..w*32+31)
  {
    bf16x8 aq[2][2];
#pragma unroll
    for (int Mt = 0; Mt < 2; ++Mt) {
      int row = w * 32 + Mt * 16 + lo16;
#pragma unroll
      for (int Ks = 0; Ks < 2; ++Ks)
        aq[Mt][Ks] = *(const bf16x8*)&wbf[row * 64 + Ks * 32 + (hi4 << 3)];
    }
#pragma unroll
    for (int Nt = 0; Nt < 8; ++Nt) {
      const int p = Nt * 16 + lo16;
      f32x4 acc[2];
      acc[0] = (f32x4){0.f, 0.f, 0.f, 0.f};
      acc[1] = (f32x4){0.f, 0.f, 0.f, 0.f};
#pragma unroll
      for (int Ks = 0; Ks < 2; ++Ks) {
        int g = Ks * 4 + hi4;
        bf16x8 bfr = *(const bf16x8*)&xs[p * 64 + ((g ^ (p & 7)) << 3)];
#pragma unroll
        for (int Mt = 0; Mt < 2; ++Mt)
          acc[Mt] = __builtin_amdgcn_mfma_f32_16x16x32_bf16(aq[Mt][Ks], bfr,
                                                            acc[Mt], 0, 0, 0);
      }
      float m = acc[0][0];
#pragma unroll
      for (int r = 1; r < 4; ++r) m = fmaxf(m, acc[0][r]);
#pragma unroll
      for (int r = 0; r < 4; ++r) m = fmaxf(m, acc[1][r]);
      m = fmaxf(m, __shfl_xor(m, 16));
      m = fmaxf(m, __shfl_xor(m, 32));
      float s = 0.f;
#pragma unroll
      for (int Mt = 0; Mt < 2; ++Mt)
#pragma unroll
        for (int r = 0; r < 4; ++r) {
          acc[Mt][r] = __expf(acc[Mt][r] - m);
          s += acc[Mt][r];
        }
      s += __shfl_xor(s, 16);
      s += __shfl_xor(s, 32);
      const float inv = 1.f / s;
#pragma unroll
      for (int Mt = 0; Mt < 2; ++Mt) {
#pragma unroll
        for (int pr = 0; pr < 2; ++pr) {
          int hd = w * 32 + Mt * 16 + hi4 * 4 + pr * 2;
          int g = hd >> 3;
          int col = ((g ^ (p & 15)) << 3) | (hd & 7);
          *(unsigned int*)&qsl[p * 128 + col] =
              pack2(acc[Mt][pr * 2] * inv, acc[Mt][pr * 2 + 1] * inv);
        }
      }
    }
  }
  __syncthreads();

  // ---- GEMM-Y: y[o][p] = sum_hd Weff[o][hd]*qs[hd][p]; wave w: Nt {2w,2w+1}
  f32x4 accY[2][4];
#pragma unroll
  for (int nt = 0; nt < 2; ++nt)
#pragma unroll
    for (int Mt = 0; Mt < 4; ++Mt) accY[nt][Mt] = (f32x4){0.f, 0.f, 0.f, 0.f};
#pragma unroll
  for (int nt = 0; nt < 2; ++nt) {
    const int p = (w * 2 + nt) * 16 + lo16;
#pragma unroll
    for (int Ks = 0; Ks < 4; ++Ks) {
      int g = Ks * 4 + hi4;
      bf16x8 bq = *(const bf16x8*)&qsl[p * 128 + ((g ^ (p & 15)) << 3)];
#pragma unroll
      for (int Mt = 0; Mt < 4; ++Mt) {
        int o = Mt * 16 + lo16;
        bf16x8 aw = *(const bf16x8*)&web[o * 128 + (g << 3)];
        accY[nt][Mt] = __builtin_amdgcn_mfma_f32_16x16x32_bf16(aw, bq,
                                                               accY[nt][Mt], 0, 0, 0);
      }
    }
  }

  // ---- epilogue: bias, store y, accumulate per-lane BN partials
  float sacc[16], qacc[16];
#pragma unroll
  for (int i = 0; i < 16; ++i) { sacc[i] = 0.f; qacc[i] = 0.f; }
#pragma unroll
  for (int nt = 0; nt < 2; ++nt) {
    const int p = p0 + (w * 2 + nt) * 16 + lo16;
#pragma unroll
    for (int Mt = 0; Mt < 4; ++Mt) {
#pragma unroll
      for (int r = 0; r < 4; ++r) {
        int o = Mt * 16 + hi4 * 4 + r;
        float val = accY[nt][Mt][r] + bo[o];
        y[((size_t)(b * 64 + o) << 14) + p] = val;
        sacc[Mt * 4 + r] += val;
        qacc[Mt * 4 + r] += val * val;
      }
    }
  }
  // intra-wave reduce across the 16 lanes sharing an o-set
#pragma unroll
  for (int off = 1; off < 16; off <<= 1) {
#pragma unroll
    for (int i = 0; i < 16; ++i) {
      sacc[i] += __shfl_xor(sacc[i], off);
      qacc[i] += __shfl_xor(qacc[i], off);
    }
  }
  // cross-wave reduce in LDS (reuse qsl region), one coalesced row per block
  __syncthreads();  // all GEMM-Y qsl reads complete
  float* red = (float*)qsl;  // 4 waves * 128 floats
  if (lo16 == 0) {
#pragma unroll
    for (int i = 0; i < 16; ++i) {
      int o = (i >> 2) * 16 + hi4 * 4 + (i & 3);
      red[w * 128 + o] = sacc[i];
      red[w * 128 + 64 + o] = qacc[i];
    }
  }
  __syncthreads();
  if (t < 128) {
    float s = red[t] + red[128 + t] + red[256 + t] + red[384 + t];
    pstats[(size_t)blockIdx.x * 128 + t] = s;
  }
}

// =====================================================================
// kred: reduce pstats[2048][128] -> ssum[64], ssq[64]. grid 128, block 256
// =====================================================================
__global__ __launch_bounds__(256) void kred(const float* __restrict__ pstats,
                                            float* __restrict__ ssum,
                                            float* __restrict__ ssq) {
  const int t = threadIdx.x;
  const int which = blockIdx.x >> 6;  // 0: sum, 1: sumsq
  const int o = blockIdx.x & 63;
  const int base = which * 64 + o;
  float s = 0.f;
#pragma unroll
  for (int i = 0; i < 8; ++i)
    s += pstats[(size_t)(i * 256 + t) * 128 + base];
#pragma unroll
  for (int off = 32; off > 0; off >>= 1) s += __shfl_down(s, off);
  __shared__ float ls[4];
  if ((t & 63) == 0) ls[t >> 6] = s;
  __syncthreads();
  if (t == 0) {
    float r = ls[0] + ls[1] + ls[2] + ls[3];
    if (which) ssq[o] = r; else ssum[o] = r;
  }
}

// =====================================================================
// kbn: in-place BatchNorm apply (grid 2048, block 256)
// =====================================================================
__global__ __launch_bounds__(256) void kbn(float* __restrict__ y,
                                           const float* __restrict__ ssum,
                                           const float* __restrict__ ssq,
                                           const float* __restrict__ gamma,
                                           const float* __restrict__ beta) {
  const int t = threadIdx.x;
  const size_t base = (size_t)blockIdx.x * 8192;
  const int o = (blockIdx.x >> 1) & 63;
  const float invn = 1.f / 262144.f;
  const float mean = ssum[o] * invn;
  const float var = ssq[o] * invn - mean * mean;
  const float g = gamma[o] * rsqrtf(var + EPSV);
  const float sh = beta[o] - mean * g;
#pragma unroll
  for (int it = 0; it < 8; ++it) {
    float4 v = *(float4*)&y[base + it * 1024 + t * 4];
    v.x = v.x * g + sh;
    v.y = v.y * g + sh;
    v.z = v.z * g + sh;
    v.w = v.w * g + sh;
    *(float4*)&y[base + it * 1024 + t * 4] = v;
  }
}

// =====================================================================
// ============ Fallback path (round-0, known-correct) ==================
// =====================================================================
__global__ __launch_bounds__(256) void kctx0(const float* __restrict__ x,
                                             const float* __restrict__ wq,
                                             float* __restrict__ ctxT) {
  __shared__ float kT[32 * 256];
  __shared__ float vT[32 * 256];
  const int t = threadIdx.x;
  const int b = blockIdx.x >> 5;
  const int tile = blockIdx.x & 31;
  const int d0 = (t & 15) << 1;
  const int e0 = (t >> 4) << 1;
  float acc[4][2][2];
#pragma unroll
  for (int h = 0; h < 4; ++h)
#pragma unroll
    for (int i = 0; i < 2; ++i)
#pragma unroll
      for (int j = 0; j < 2; ++j) acc[h][i][j] = 0.f;
  for (int chunk = 0; chunk < 2; ++chunk) {
    const int p = (tile << 9) + (chunk << 8) + t;
    float xr[64];
#pragma unroll
    for (int c = 0; c < 64; ++c) xr[c] = x[((size_t)(b * 64 + c) << 14) + p];
#pragma unroll
    for (int h = 0; h < 4; ++h) {
      float kk[32];
#pragma unroll
      for (int i = 0; i < 32; ++i) {
        const float* wr = wq + (128 + h * 32 + i) * 64;
        float a = 0.f;
#pragma unroll
        for (int c = 0; c < 64; ++c) a = fmaf(wr[c], xr[c], a);
        kk[i] = a;
      }
      float m = kk[0];
#pragma unroll
      for (int i = 1; i < 32; ++i) m = fmaxf(m, kk[i]);
      float s = 0.f;
#pragma unroll
      for (int i = 0; i < 32; ++i) { kk[i] = __expf(kk[i] - m); s += kk[i]; }
      const float inv = 1.f / s;
      float vv[32];
#pragma unroll
      for (int i = 0; i < 32; ++i) {
        const float* wr = wq + (256 + h * 32 + i) * 64;
        float a = 0.f;
#pragma unroll
        for (int c = 0; c < 64; ++c) a = fmaf(wr[c], xr[c], a);
        vv[i] = a;
      }
      __syncthreads();
#pragma unroll
      for (int i = 0; i < 32; ++i) kT[i * 256 + (t ^ (2 * i))] = kk[i] * inv;
#pragma unroll
      for (int i = 0; i < 32; ++i) vT[i * 256 + t] = vv[i];
      __syncthreads();
#pragma unroll 2
      for (int p2 = 0; p2 < 256; p2 += 2) {
        const float2 k0 = *(const float2*)&kT[d0 * 256 + (p2 ^ (2 * d0))];
        const float2 k1 = *(const float2*)&kT[(d0 + 1) * 256 + (p2 ^ (2 * (d0 + 1)))];
        const float2 v0 = *(const float2*)&vT[e0 * 256 + p2];
        const float2 v1 = *(const float2*)&vT[(e0 + 1) * 256 + p2];
        acc[h][0][0] += k0.x * v0.x + k0.y * v0.y;
        acc[h][0][1] += k0.x * v1.x + k0.y * v1.y;
        acc[h][1][0] += k1.x * v0.x + k1.y * v0.y;
        acc[h][1][1] += k1.x * v1.x + k1.y * v1.y;
      }
    }
  }
#pragma unroll
  for (int h = 0; h < 4; ++h)
#pragma unroll
    for (int i = 0; i < 2; ++i)
#pragma unroll
      for (int j = 0; j < 2; ++j)
        atomicAdd(&ctxT[(((b * 4 + h) * 32) + (e0 + j)) * 32 + (d0 + i)],
                  acc[h][i][j]);
}

__global__ __launch_bounds__(256) void kout0(const float* __restrict__ x,
                                             const float* __restrict__ wq,
                                             const float* __restrict__ wo,
                                             const float* __restrict__ bo,
                                             const float* __restrict__ ctxT,
                                             float* __restrict__ y) {
  __shared__ float cl[4096];
  const int t = threadIdx.x;
  const int b = blockIdx.x >> 6;
  const int tile = blockIdx.x & 63;
  const int p = (tile << 8) + t;
#pragma unroll
  for (int i = 0; i < 16; ++i) cl[i * 256 + t] = ctxT[(b << 12) + i * 256 + t];
  __syncthreads();
  float xr[64];
#pragma unroll
  for (int c = 0; c < 64; ++c) xr[c] = x[((size_t)(b * 64 + c) << 14) + p];
  float y0[64];
#pragma unroll
  for (int o = 0; o < 64; ++o) y0[o] = 0.f;
  for (int h = 0; h < 4; ++h) {
    float q[32];
#pragma unroll
    for (int i = 0; i < 32; ++i) {
      const float* wr = wq + (h * 32 + i) * 64;
      float a = 0.f;
#pragma unroll
      for (int c = 0; c < 64; ++c) a = fmaf(wr[c], xr[c], a);
      q[i] = a;
    }
    float m = q[0];
#pragma unroll
    for (int i = 1; i < 32; ++i) m = fmaxf(m, q[i]);
    float s = 0.f;
#pragma unroll
    for (int i = 0; i < 32; ++i) { q[i] = __expf(q[i] - m); s += q[i]; }
    const float inv = SCALEQ / s;
#pragma unroll
    for (int i = 0; i < 32; ++i) q[i] *= inv;
    float oh[32];
#pragma unroll
    for (int e = 0; e < 32; ++e) {
      const float* cr = &cl[(h * 32 + e) * 32];
      float a = 0.f;
#pragma unroll
      for (int d = 0; d < 32; ++d) a = fmaf(cr[d], q[d], a);
      oh[e] = a;
    }
#pragma unroll
    for (int o = 0; o < 64; ++o) {
      const float* wr = wo + o * 128 + h * 32;
      float a = y0[o];
#pragma unroll
      for (int e = 0; e < 32; ++e) a = fmaf(wr[e], oh[e], a);
      y0[o] = a;
    }
  }
#pragma unroll
  for (int o = 0; o < 64; ++o)
    y[((size_t)(b * 64 + o) << 14) + p] = y0[o] + bo[o];
}

__global__ __launch_bounds__(256) void kstats0(const float* __restrict__ y,
                                               float* __restrict__ ssum,
                                               float* __restrict__ ssq) {
  const int t = threadIdx.x;
  const size_t base = (size_t)blockIdx.x * 8192;
  const int o = (blockIdx.x >> 1) & 63;
  float s = 0.f, q = 0.f;
#pragma unroll
  for (int it = 0; it < 8; ++it) {
    const float4 v = *(const float4*)&y[base + it * 1024 + t * 4];
    s += v.x + v.y + v.z + v.w;
    q += v.x * v.x + v.y * v.y + v.z * v.z + v.w * v.w;
  }
#pragma unroll
  for (int off = 32; off > 0; off >>= 1) {
    s += __shfl_down(s, off);
    q += __shfl_down(q, off);
  }
  __shared__ float ls[4], lq[4];
  if ((t & 63) == 0) { ls[t >> 6] = s; lq[t >> 6] = q; }
  __syncthreads();
  if (t == 0) {
    atomicAdd(&ssum[o], ls[0] + ls[1] + ls[2] + ls[3]);
    atomicAdd(&ssq[o], lq[0] + lq[1] + lq[2] + lq[3]);
  }
}

// =====================================================================
extern "C" void kernel_launch(void* const* d_in, const int* in_sizes, int n_in,
                              void* d_out, int out_size, void* d_ws, size_t ws_size,
                              hipStream_t stream) {
  (void)in_sizes; (void)n_in; (void)out_size;
  const float* x     = (const float*)d_in[0];
  const float* wq    = (const float*)d_in[1];
  const float* wo    = (const float*)d_in[2];
  const float* bo    = (const float*)d_in[3];
  const float* gamma = (const float*)d_in[4];
  const float* beta  = (const float*)d_in[5];
  float* out = (float*)d_out;

  // workspace layout (bytes):
  // ctx    @ 0        : 262144   (65536 f32)
  // ssum   @ 262144   : 256      (64 f32)
  // ssq    @ 262400   : 256      (64 f32)
  // weffbf @ 262656   : 262144   (16*64*128 bf16)
  // wbf    @ 524800   : 49152    (384*64 bf16)
  // pstats @ 573952   : 1048576  (2048*128 f32)
  // xsw    @ 1622528  : 33554432 (16*16384*64 bf16)
  float* ctx  = (float*)d_ws;
  float* ssum = (float*)((char*)d_ws + 262144);
  float* ssq  = (float*)((char*)d_ws + 262400);
  unsigned short* weffbf = (unsigned short*)((char*)d_ws + 262656);
  unsigned short* wbf    = (unsigned short*)((char*)d_ws + 524800);
  float* pstats          = (float*)((char*)d_ws + 573952);
  unsigned short* xsw    = (unsigned short*)((char*)d_ws + 1622528);
  const size_t need = 1622528 + (size_t)16 * 16384 * 64 * 2;

  hipMemsetAsync(d_ws, 0, 262656, stream);  // ctx + ssum + ssq
  if (ws_size >= need) {
    kwconv<<<24, 256, 0, stream>>>(wq, wbf);
    ktr<<<1024, 256, 0, stream>>>(x, xsw);
    kctx<<<2048, 256, 0, stream>>>(xsw, wbf, ctx);
    kweff<<<16, 256, 0, stream>>>(ctx, wo, weffbf);
    kout<<<2048, 256, 0, stream>>>(xsw, wbf, weffbf, bo, out, pstats);
    kred<<<128, 256, 0, stream>>>(pstats, ssum, ssq);
    kbn<<<2048, 256, 0, stream>>>(out, ssum, ssq, gamma, beta);
  } else {
    kctx0<<<512, 256, 0, stream>>>(x, wq, ctx);
    kout0<<<1024, 256, 0, stream>>>(x, wq, wo, bo, ctx, out);
    kstats0<<<2048, 256, 0, stream>>>(out, ssum, ssq);
    kbn<<<2048, 256, 0, stream>>>(out, ssum, ssq, gamma, beta);
  }
}

// Round 7
// 247.184 us; speedup vs baseline: 7.3860x; 1.4678x over previous
//
#include <hip/hip_runtime.h>

typedef __attribute__((ext_vector_type(8))) short bf16x8;
typedef __attribute__((ext_vector_type(4))) float f32x4;

#define SCALEQ 0.17677669529663687f  // 32^-0.5
#define EPSV 1e-5f

__device__ inline unsigned short f2bf(float f) {
  unsigned int u = __float_as_uint(f);
  return (unsigned short)((u + 0x7FFFu + ((u >> 16) & 1u)) >> 16);
}
__device__ inline unsigned int pack2(float a, float b) {
  return (unsigned int)f2bf(a) | ((unsigned int)f2bf(b) << 16);
}

// =====================================================================
// kwconv: wqkv fp32 [384][64] -> wbf bf16 [384][64]. grid 24, block 256.
// =====================================================================
__global__ __launch_bounds__(256) void kwconv(const float* __restrict__ wqkv,
                                              unsigned short* __restrict__ wbf) {
  const int i = blockIdx.x * 256 + threadIdx.x;  // 6144 threads * 4 elems
  const float4 v = *(const float4*)&wqkv[i * 4];
  *(uint2*)&wbf[i * 4] = make_uint2(pack2(v.x, v.y), pack2(v.z, v.w));
}

// =====================================================================
// ktr: x [b][c][p] fp32  ->  xsw [b][p][c] bf16, granule-swizzled:
//      slot gout of row p holds source granule gout ^ (p&7) (8 bf16/granule)
// grid 16*64=1024, block 256. LDS transpose buffer XOR-swizzled.
// =====================================================================
__global__ __launch_bounds__(256) void ktr(const float* __restrict__ x,
                                           unsigned short* __restrict__ xsw) {
  __shared__ float xl[64][256];
  const int t = threadIdx.x;
  const int b = blockIdx.x >> 6;
  const int p0 = (blockIdx.x & 63) << 8;
#pragma unroll
  for (int i = 0; i < 16; ++i) {
    int s = i * 256 + t;            // 4096 float4 slots: c = s>>6, f4 = s&63
    int c = s >> 6, f4 = s & 63;
    float4 v = *(const float4*)&x[((size_t)(b * 64 + c) << 14) + p0 + f4 * 4];
    *(float4*)&xl[c][(f4 * 4) ^ ((c >> 3) << 2)] = v;
  }
  __syncthreads();
#pragma unroll
  for (int i = 0; i < 8; ++i) {
    int a = i * 256 + t;            // 2048 granule slots: row = a>>3, gout = a&7
    int row = a >> 3, gout = a & 7;
    int gsrc = gout ^ (row & 7);
    int col = row ^ (gsrc << 2);    // same swizzle on read side
    unsigned int w0 = pack2(xl[gsrc * 8 + 0][col], xl[gsrc * 8 + 1][col]);
    unsigned int w1 = pack2(xl[gsrc * 8 + 2][col], xl[gsrc * 8 + 3][col]);
    unsigned int w2 = pack2(xl[gsrc * 8 + 4][col], xl[gsrc * 8 + 5][col]);
    unsigned int w3 = pack2(xl[gsrc * 8 + 6][col], xl[gsrc * 8 + 7][col]);
    size_t off = ((size_t)(b * 16384 + p0 + row) * 64) + gout * 8;
    *(uint4*)&xsw[off] = make_uint4(w0, w1, w2, w3);
  }
}

// =====================================================================
// kctx: ALL-MFMA context kernel. grid 16*64=1024, block 256 (4 waves).
// Each block: 256 positions (2 chunks of 128). Per chunk, per head:
//   GEMM1: kv = Wkv * X (waves split N-tiles), softmax(k) per position,
//   stage k,v bf16 -> kvb[64][128] (granule ^= row&7 swizzle),
//   GEMM2: wave w owns ctx quadrant (d-blk w>>1, e-blk w&1), K=128, 4 MFMAs.
// ctx quadrants accumulate in registers across chunks; atomics once/block.
// =====================================================================
__global__ __launch_bounds__(256) void kctx(const unsigned short* __restrict__ xsw,
                                            const unsigned short* __restrict__ wbf,
                                            float* __restrict__ ctx) {
  __shared__ __align__(16) unsigned short kvb[64 * 128];  // 16KB: rows 0-31 k, 32-63 v
  const int t = threadIdx.x;
  const int l = t & 63;
  const int w = t >> 6;
  const int b = blockIdx.x >> 6;
  const int pt = blockIdx.x & 63;
  const int lo16 = l & 15, hi4 = l >> 4;

  f32x4 acc2[4];
#pragma unroll
  for (int h = 0; h < 4; ++h) acc2[h] = (f32x4){0.f, 0.f, 0.f, 0.f};

  for (int chunk = 0; chunk < 2; ++chunk) {
    const unsigned short* xb =
        xsw + (size_t)(b * 16384 + pt * 256 + chunk * 128) * 64;
    for (int h = 0; h < 4; ++h) {
      // ---- A-fragments from wbf (L1-hot): k rows 128+h*32.., v rows 256+h*32..
      bf16x8 afr[4][2];
#pragma unroll
      for (int Mt = 0; Mt < 4; ++Mt) {
        int row = (Mt < 2) ? (128 + h * 32 + Mt * 16 + lo16)
                           : (256 + h * 32 + (Mt - 2) * 16 + lo16);
#pragma unroll
        for (int Ks = 0; Ks < 2; ++Ks)
          afr[Mt][Ks] = *(const bf16x8*)&wbf[row * 64 + Ks * 32 + (hi4 << 3)];
      }

      // ---- GEMM1 over this wave's 2 N-tiles + softmax(k) + stage to kvb
#pragma unroll
      for (int nt = 0; nt < 2; ++nt) {
        const int p = (w * 2 + nt) * 16 + lo16;  // 0..127
        f32x4 acc[4];
#pragma unroll
        for (int Mt = 0; Mt < 4; ++Mt) acc[Mt] = (f32x4){0.f, 0.f, 0.f, 0.f};
#pragma unroll
        for (int Ks = 0; Ks < 2; ++Ks) {
          int g = Ks * 4 + hi4;
          bf16x8 bfr = *(const bf16x8*)&xb[p * 64 + ((g ^ (p & 7)) << 3)];
#pragma unroll
          for (int Mt = 0; Mt < 4; ++Mt)
            acc[Mt] = __builtin_amdgcn_mfma_f32_16x16x32_bf16(afr[Mt][Ks], bfr,
                                                              acc[Mt], 0, 0, 0);
        }
        // softmax over 32 k-features of this position
        float m = acc[0][0];
#pragma unroll
        for (int r = 1; r < 4; ++r) m = fmaxf(m, acc[0][r]);
#pragma unroll
        for (int r = 0; r < 4; ++r) m = fmaxf(m, acc[1][r]);
        m = fmaxf(m, __shfl_xor(m, 16));
        m = fmaxf(m, __shfl_xor(m, 32));
        float s = 0.f;
#pragma unroll
        for (int Mt = 0; Mt < 2; ++Mt)
#pragma unroll
          for (int r = 0; r < 4; ++r) {
            acc[Mt][r] = __expf(acc[Mt][r] - m);
            s += acc[Mt][r];
          }
        s += __shfl_xor(s, 16);
        s += __shfl_xor(s, 32);
        const float inv = 1.f / s;
        // stage bf16 into kvb with granule^(row&7) swizzle
#pragma unroll
        for (int Mt = 0; Mt < 4; ++Mt) {
#pragma unroll
          for (int r = 0; r < 4; ++r) {
            int row = ((Mt < 2) ? Mt * 16 : 32 + (Mt - 2) * 16) + hi4 * 4 + r;
            float val = (Mt < 2) ? acc[Mt][r] * inv : acc[Mt][r];
            kvb[row * 128 + (((p >> 3) ^ (row & 7)) << 3) + (p & 7)] = f2bf(val);
          }
        }
      }
      __syncthreads();

      // ---- GEMM2: quadrant (w>>1, w&1), K = 128 positions
      const int arow = ((w >> 1) << 4) + lo16;       // k row (d)
      const int brow = 32 + ((w & 1) << 4) + lo16;   // v row (e)
#pragma unroll
      for (int Ks2 = 0; Ks2 < 4; ++Ks2) {
        int j8 = Ks2 * 4 + hi4;
        bf16x8 ka = *(const bf16x8*)&kvb[arow * 128 + ((j8 ^ (arow & 7)) << 3)];
        bf16x8 va = *(const bf16x8*)&kvb[brow * 128 + ((j8 ^ (brow & 7)) << 3)];
        acc2[h] = __builtin_amdgcn_mfma_f32_16x16x32_bf16(ka, va, acc2[h], 0, 0, 0);
      }
      __syncthreads();  // before next head overwrites kvb
    }
  }

  // ---- one atomic pass per block; quadrants are disjoint across waves
  const int d0 = ((w >> 1) << 4) + hi4 * 4;
  const int e  = ((w & 1) << 4) + lo16;
#pragma unroll
  for (int h = 0; h < 4; ++h)
#pragma unroll
    for (int r = 0; r < 4; ++r)
      atomicAdd(&ctx[(size_t)((b * 4 + h) * 32 + d0 + r) * 32 + e], acc2[h][r]);
}

// =====================================================================
// kweff: Weff[b][o][h*32+d] = SCALEQ * sum_e Wo[o][h*32+e] * ctx[b][h][d][e]
//        emitted directly as bf16. grid 16, block 256
// =====================================================================
__global__ __launch_bounds__(256) void kweff(const float* __restrict__ ctx,
                                             const float* __restrict__ wo,
                                             unsigned short* __restrict__ weffbf) {
  __shared__ float ctxl[4 * 1064];  // [h][d][33] (+8 pad per h)
  const int t = threadIdx.x;
  const int b = blockIdx.x;
#pragma unroll
  for (int i = 0; i < 16; ++i) {
    int idx = i * 256 + t;
    int h = idx >> 10, d = (idx >> 5) & 31, e = idx & 31;
    ctxl[h * 1064 + d * 33 + e] = ctx[(size_t)(b * 4 + h) * 1024 + d * 32 + e];
  }
  __syncthreads();
  const int o = t >> 2, h = t & 3;
  float wr[32];
#pragma unroll
  for (int e4 = 0; e4 < 8; ++e4) {
    float4 v = *(const float4*)&wo[o * 128 + h * 32 + e4 * 4];
    wr[e4 * 4] = v.x; wr[e4 * 4 + 1] = v.y;
    wr[e4 * 4 + 2] = v.z; wr[e4 * 4 + 3] = v.w;
  }
  for (int d = 0; d < 32; ++d) {
    float s = 0.f;
#pragma unroll
    for (int e = 0; e < 32; ++e) s = fmaf(wr[e], ctxl[h * 1064 + d * 33 + e], s);
    weffbf[(size_t)b * 8192 + o * 128 + h * 32 + d] = f2bf(s * SCALEQ);
  }
}

// =====================================================================
// kout: q = softmax(Wq*X) via MFMA; y = Weff*qs + bias via MFMA;
//       per-block BN partials (NO global atomics). grid 2048, block 256
// =====================================================================
__global__ __launch_bounds__(256) void kout(const unsigned short* __restrict__ xsw,
                                            const unsigned short* __restrict__ wbf,
                                            const unsigned short* __restrict__ weffbf,
                                            const float* __restrict__ bo,
                                            float* __restrict__ y,
                                            float* __restrict__ pstats) {
  __shared__ __align__(16) unsigned short xs[128 * 64];    // 16KB
  __shared__ __align__(16) unsigned short qsl[128 * 128];  // 32KB [p][hd] swz g^=(p&15)
  const int t = threadIdx.x;
  const int l = t & 63;
  const int w = t >> 6;
  const int b = blockIdx.x >> 7;
  const int p0 = (blockIdx.x & 127) << 7;
  const int lo16 = l & 15, hi4 = l >> 4;
  const unsigned short* web = weffbf + ((size_t)b << 13);

  {  // stage xs (linear copy; swizzle pre-baked in global layout)
    const uint4* src = (const uint4*)&xsw[(size_t)(b * 16384 + p0) * 64];
    uint4* dst = (uint4*)xs;
#pragma unroll
    for (int i = 0; i < 4; ++i) dst[i * 256 + t] = src[i * 256 + t];
  }
  __syncthreads();

  // ---- GEMM-Q: wave w = head w (q rows w*32..w*32+31)
  {
    bf16x8 aq[2][2];
#pragma unroll
    for (int Mt = 0; Mt < 2; ++Mt) {
      int row = w * 32 + Mt * 16 + lo16;
#pragma unroll
      for (int Ks = 0; Ks < 2; ++Ks)
        aq[Mt][Ks] = *(const bf16x8*)&wbf[row * 64 + Ks * 32 + (hi4 << 3)];
    }
#pragma unroll
    for (int Nt = 0; Nt < 8; ++Nt) {
      const int p = Nt * 16 + lo16;
      f32x4 acc[2];
      acc[0] = (f32x4){0.f, 0.f, 0.f, 0.f};
      acc[1] = (f32x4){0.f, 0.f, 0.f, 0.f};
#pragma unroll
      for (int Ks = 0; Ks < 2; ++Ks) {
        int g = Ks * 4 + hi4;
        bf16x8 bfr = *(const bf16x8*)&xs[p * 64 + ((g ^ (p & 7)) << 3)];
#pragma unroll
        for (int Mt = 0; Mt < 2; ++Mt)
          acc[Mt] = __builtin_amdgcn_mfma_f32_16x16x32_bf16(aq[Mt][Ks], bfr,
                                                            acc[Mt], 0, 0, 0);
      }
      float m = acc[0][0];
#pragma unroll
      for (int r = 1; r < 4; ++r) m = fmaxf(m, acc[0][r]);
#pragma unroll
      for (int r = 0; r < 4; ++r) m = fmaxf(m, acc[1][r]);
      m = fmaxf(m, __shfl_xor(m, 16));
      m = fmaxf(m, __shfl_xor(m, 32));
      float s = 0.f;
#pragma unroll
      for (int Mt = 0; Mt < 2; ++Mt)
#pragma unroll
        for (int r = 0; r < 4; ++r) {
          acc[Mt][r] = __expf(acc[Mt][r] - m);
          s += acc[Mt][r];
        }
      s += __shfl_xor(s, 16);
      s += __shfl_xor(s, 32);
      const float inv = 1.f / s;
#pragma unroll
      for (int Mt = 0; Mt < 2; ++Mt) {
#pragma unroll
        for (int pr = 0; pr < 2; ++pr) {
          int hd = w * 32 + Mt * 16 + hi4 * 4 + pr * 2;
          int g = hd >> 3;
          int col = ((g ^ (p & 15)) << 3) | (hd & 7);
          *(unsigned int*)&qsl[p * 128 + col] =
              pack2(acc[Mt][pr * 2] * inv, acc[Mt][pr * 2 + 1] * inv);
        }
      }
    }
  }
  __syncthreads();

  // ---- GEMM-Y: y[o][p] = sum_hd Weff[o][hd]*qs[hd][p]; wave w: Nt {2w,2w+1}
  f32x4 accY[2][4];
#pragma unroll
  for (int nt = 0; nt < 2; ++nt)
#pragma unroll
    for (int Mt = 0; Mt < 4; ++Mt) accY[nt][Mt] = (f32x4){0.f, 0.f, 0.f, 0.f};
#pragma unroll
  for (int nt = 0; nt < 2; ++nt) {
    const int p = (w * 2 + nt) * 16 + lo16;
#pragma unroll
    for (int Ks = 0; Ks < 4; ++Ks) {
      int g = Ks * 4 + hi4;
      bf16x8 bq = *(const bf16x8*)&qsl[p * 128 + ((g ^ (p & 15)) << 3)];
#pragma unroll
      for (int Mt = 0; Mt < 4; ++Mt) {
        int o = Mt * 16 + lo16;
        bf16x8 aw = *(const bf16x8*)&web[o * 128 + (g << 3)];
        accY[nt][Mt] = __builtin_amdgcn_mfma_f32_16x16x32_bf16(aw, bq,
                                                               accY[nt][Mt], 0, 0, 0);
      }
    }
  }

  // ---- epilogue: bias, store y, accumulate per-lane BN partials
  float sacc[16], qacc[16];
#pragma unroll
  for (int i = 0; i < 16; ++i) { sacc[i] = 0.f; qacc[i] = 0.f; }
#pragma unroll
  for (int nt = 0; nt < 2; ++nt) {
    const int p = p0 + (w * 2 + nt) * 16 + lo16;
#pragma unroll
    for (int Mt = 0; Mt < 4; ++Mt) {
#pragma unroll
      for (int r = 0; r < 4; ++r) {
        int o = Mt * 16 + hi4 * 4 + r;
        float val = accY[nt][Mt][r] + bo[o];
        y[((size_t)(b * 64 + o) << 14) + p] = val;
        sacc[Mt * 4 + r] += val;
        qacc[Mt * 4 + r] += val * val;
      }
    }
  }
  // intra-wave reduce across the 16 lanes sharing an o-set
#pragma unroll
  for (int off = 1; off < 16; off <<= 1) {
#pragma unroll
    for (int i = 0; i < 16; ++i) {
      sacc[i] += __shfl_xor(sacc[i], off);
      qacc[i] += __shfl_xor(qacc[i], off);
    }
  }
  // cross-wave reduce in LDS (reuse qsl region), one coalesced row per block
  __syncthreads();  // all GEMM-Y qsl reads complete
  float* red = (float*)qsl;  // 4 waves * 128 floats
  if (lo16 == 0) {
#pragma unroll
    for (int i = 0; i < 16; ++i) {
      int o = (i >> 2) * 16 + hi4 * 4 + (i & 3);
      red[w * 128 + o] = sacc[i];
      red[w * 128 + 64 + o] = qacc[i];
    }
  }
  __syncthreads();
  if (t < 128) {
    float s = red[t] + red[128 + t] + red[256 + t] + red[384 + t];
    pstats[(size_t)blockIdx.x * 128 + t] = s;
  }
}

// =====================================================================
// kred: reduce pstats[2048][128] -> ssum[64], ssq[64]. grid 128, block 256
// =====================================================================
__global__ __launch_bounds__(256) void kred(const float* __restrict__ pstats,
                                            float* __restrict__ ssum,
                                            float* __restrict__ ssq) {
  const int t = threadIdx.x;
  const int which = blockIdx.x >> 6;  // 0: sum, 1: sumsq
  const int o = blockIdx.x & 63;
  const int base = which * 64 + o;
  float s = 0.f;
#pragma unroll
  for (int i = 0; i < 8; ++i)
    s += pstats[(size_t)(i * 256 + t) * 128 + base];
#pragma unroll
  for (int off = 32; off > 0; off >>= 1) s += __shfl_down(s, off);
  __shared__ float ls[4];
  if ((t & 63) == 0) ls[t >> 6] = s;
  __syncthreads();
  if (t == 0) {
    float r = ls[0] + ls[1] + ls[2] + ls[3];
    if (which) ssq[o] = r; else ssum[o] = r;
  }
}

// =====================================================================
// kbn: in-place BatchNorm apply (grid 2048, block 256)
// =====================================================================
__global__ __launch_bounds__(256) void kbn(float* __restrict__ y,
                                           const float* __restrict__ ssum,
                                           const float* __restrict__ ssq,
                                           const float* __restrict__ gamma,
                                           const float* __restrict__ beta) {
  const int t = threadIdx.x;
  const size_t base = (size_t)blockIdx.x * 8192;
  const int o = (blockIdx.x >> 1) & 63;
  const float invn = 1.f / 262144.f;
  const float mean = ssum[o] * invn;
  const float var = ssq[o] * invn - mean * mean;
  const float g = gamma[o] * rsqrtf(var + EPSV);
  const float sh = beta[o] - mean * g;
#pragma unroll
  for (int it = 0; it < 8; ++it) {
    float4 v = *(float4*)&y[base + it * 1024 + t * 4];
    v.x = v.x * g + sh;
    v.y = v.y * g + sh;
    v.z = v.z * g + sh;
    v.w = v.w * g + sh;
    *(float4*)&y[base + it * 1024 + t * 4] = v;
  }
}

// =====================================================================
// ============ Fallback path (round-0, known-correct) ==================
// =====================================================================
__global__ __launch_bounds__(256) void kctx0(const float* __restrict__ x,
                                             const float* __restrict__ wq,
                                             float* __restrict__ ctxT) {
  __shared__ float kT[32 * 256];
  __shared__ float vT[32 * 256];
  const int t = threadIdx.x;
  const int b = blockIdx.x >> 5;
  const int tile = blockIdx.x & 31;
  const int d0 = (t & 15) << 1;
  const int e0 = (t >> 4) << 1;
  float acc[4][2][2];
#pragma unroll
  for (int h = 0; h < 4; ++h)
#pragma unroll
    for (int i = 0; i < 2; ++i)
#pragma unroll
      for (int j = 0; j < 2; ++j) acc[h][i][j] = 0.f;
  for (int chunk = 0; chunk < 2; ++chunk) {
    const int p = (tile << 9) + (chunk << 8) + t;
    float xr[64];
#pragma unroll
    for (int c = 0; c < 64; ++c) xr[c] = x[((size_t)(b * 64 + c) << 14) + p];
#pragma unroll
    for (int h = 0; h < 4; ++h) {
      float kk[32];
#pragma unroll
      for (int i = 0; i < 32; ++i) {
        const float* wr = wq + (128 + h * 32 + i) * 64;
        float a = 0.f;
#pragma unroll
        for (int c = 0; c < 64; ++c) a = fmaf(wr[c], xr[c], a);
        kk[i] = a;
      }
      float m = kk[0];
#pragma unroll
      for (int i = 1; i < 32; ++i) m = fmaxf(m, kk[i]);
      float s = 0.f;
#pragma unroll
      for (int i = 0; i < 32; ++i) { kk[i] = __expf(kk[i] - m); s += kk[i]; }
      const float inv = 1.f / s;
      float vv[32];
#pragma unroll
      for (int i = 0; i < 32; ++i) {
        const float* wr = wq + (256 + h * 32 + i) * 64;
        float a = 0.f;
#pragma unroll
        for (int c = 0; c < 64; ++c) a = fmaf(wr[c], xr[c], a);
        vv[i] = a;
      }
      __syncthreads();
#pragma unroll
      for (int i = 0; i < 32; ++i) kT[i * 256 + (t ^ (2 * i))] = kk[i] * inv;
#pragma unroll
      for (int i = 0; i < 32; ++i) vT[i * 256 + t] = vv[i];
      __syncthreads();
#pragma unroll 2
      for (int p2 = 0; p2 < 256; p2 += 2) {
        const float2 k0 = *(const float2*)&kT[d0 * 256 + (p2 ^ (2 * d0))];
        const float2 k1 = *(const float2*)&kT[(d0 + 1) * 256 + (p2 ^ (2 * (d0 + 1)))];
        const float2 v0 = *(const float2*)&vT[e0 * 256 + p2];
        const float2 v1 = *(const float2*)&vT[(e0 + 1) * 256 + p2];
        acc[h][0][0] += k0.x * v0.x + k0.y * v0.y;
        acc[h][0][1] += k0.x * v1.x + k0.y * v1.y;
        acc[h][1][0] += k1.x * v0.x + k1.y * v0.y;
        acc[h][1][1] += k1.x * v1.x + k1.y * v1.y;
      }
    }
  }
#pragma unroll
  for (int h = 0; h < 4; ++h)
#pragma unroll
    for (int i = 0; i < 2; ++i)
#pragma unroll
      for (int j = 0; j < 2; ++j)
        atomicAdd(&ctxT[(((b * 4 + h) * 32) + (e0 + j)) * 32 + (d0 + i)],
                  acc[h][i][j]);
}

__global__ __launch_bounds__(256) void kout0(const float* __restrict__ x,
                                             const float* __restrict__ wq,
                                             const float* __restrict__ wo,
                                             const float* __restrict__ bo,
                                             const float* __restrict__ ctxT,
                                             float* __restrict__ y) {
  __shared__ float cl[4096];
  const int t = threadIdx.x;
  const int b = blockIdx.x >> 6;
  const int tile = blockIdx.x & 63;
  const int p = (tile << 8) + t;
#pragma unroll
  for (int i = 0; i < 16; ++i) cl[i * 256 + t] = ctxT[(b << 12) + i * 256 + t];
  __syncthreads();
  float xr[64];
#pragma unroll
  for (int c = 0; c < 64; ++c) xr[c] = x[((size_t)(b * 64 + c) << 14) + p];
  float y0[64];
#pragma unroll
  for (int o = 0; o < 64; ++o) y0[o] = 0.f;
  for (int h = 0; h < 4; ++h) {
    float q[32];
#pragma unroll
    for (int i = 0; i < 32; ++i) {
      const float* wr = wq + (h * 32 + i) * 64;
      float a = 0.f;
#pragma unroll
      for (int c = 0; c < 64; ++c) a = fmaf(wr[c], xr[c], a);
      q[i] = a;
    }
    float m = q[0];
#pragma unroll
    for (int i = 1; i < 32; ++i) m = fmaxf(m, q[i]);
    float s = 0.f;
#pragma unroll
    for (int i = 0; i < 32; ++i) { q[i] = __expf(q[i] - m); s += q[i]; }
    const float inv = SCALEQ / s;
#pragma unroll
    for (int i = 0; i < 32; ++i) q[i] *= inv;
    float oh[32];
#pragma unroll
    for (int e = 0; e < 32; ++e) {
      const float* cr = &cl[(h * 32 + e) * 32];
      float a = 0.f;
#pragma unroll
      for (int d = 0; d < 32; ++d) a = fmaf(cr[d], q[d], a);
      oh[e] = a;
    }
#pragma unroll
    for (int o = 0; o < 64; ++o) {
      const float* wr = wo + o * 128 + h * 32;
      float a = y0[o];
#pragma unroll
      for (int e = 0; e < 32; ++e) a = fmaf(wr[e], oh[e], a);
      y0[o] = a;
    }
  }
#pragma unroll
  for (int o = 0; o < 64; ++o)
    y[((size_t)(b * 64 + o) << 14) + p] = y0[o] + bo[o];
}

__global__ __launch_bounds__(256) void kstats0(const float* __restrict__ y,
                                               float* __restrict__ ssum,
                                               float* __restrict__ ssq) {
  const int t = threadIdx.x;
  const size_t base = (size_t)blockIdx.x * 8192;
  const int o = (blockIdx.x >> 1) & 63;
  float s = 0.f, q = 0.f;
#pragma unroll
  for (int it = 0; it < 8; ++it) {
    const float4 v = *(const float4*)&y[base + it * 1024 + t * 4];
    s += v.x + v.y + v.z + v.w;
    q += v.x * v.x + v.y * v.y + v.z * v.z + v.w * v.w;
  }
#pragma unroll
  for (int off = 32; off > 0; off >>= 1) {
    s += __shfl_down(s, off);
    q += __shfl_down(q, off);
  }
  __shared__ float ls[4], lq[4];
  if ((t & 63) == 0) { ls[t >> 6] = s; lq[t >> 6] = q; }
  __syncthreads();
  if (t == 0) {
    atomicAdd(&ssum[o], ls[0] + ls[1] + ls[2] + ls[3]);
    atomicAdd(&ssq[o], lq[0] + lq[1] + lq[2] + lq[3]);
  }
}

// =====================================================================
extern "C" void kernel_launch(void* const* d_in, const int* in_sizes, int n_in,
                              void* d_out, int out_size, void* d_ws, size_t ws_size,
                              hipStream_t stream) {
  (void)in_sizes; (void)n_in; (void)out_size;
  const float* x     = (const float*)d_in[0];
  const float* wq    = (const float*)d_in[1];
  const float* wo    = (const float*)d_in[2];
  const float* bo    = (const float*)d_in[3];
  const float* gamma = (const float*)d_in[4];
  const float* beta  = (const float*)d_in[5];
  float* out = (float*)d_out;

  // workspace layout (bytes):
  // ctx    @ 0        : 262144   (65536 f32)
  // ssum   @ 262144   : 256      (64 f32)
  // ssq    @ 262400   : 256      (64 f32)
  // weffbf @ 262656   : 262144   (16*64*128 bf16)
  // wbf    @ 524800   : 49152    (384*64 bf16)
  // pstats @ 573952   : 1048576  (2048*128 f32)
  // xsw    @ 1622528  : 33554432 (16*16384*64 bf16)
  float* ctx  = (float*)d_ws;
  float* ssum = (float*)((char*)d_ws + 262144);
  float* ssq  = (float*)((char*)d_ws + 262400);
  unsigned short* weffbf = (unsigned short*)((char*)d_ws + 262656);
  unsigned short* wbf    = (unsigned short*)((char*)d_ws + 524800);
  float* pstats          = (float*)((char*)d_ws + 573952);
  unsigned short* xsw    = (unsigned short*)((char*)d_ws + 1622528);
  const size_t need = 1622528 + (size_t)16 * 16384 * 64 * 2;

  hipMemsetAsync(d_ws, 0, 262656, stream);  // ctx + ssum + ssq
  if (ws_size >= need) {
    kwconv<<<24, 256, 0, stream>>>(wq, wbf);
    ktr<<<1024, 256, 0, stream>>>(x, xsw);
    kctx<<<1024, 256, 0, stream>>>(xsw, wbf, ctx);
    kweff<<<16, 256, 0, stream>>>(ctx, wo, weffbf);
    kout<<<2048, 256, 0, stream>>>(xsw, wbf, weffbf, bo, out, pstats);
    kred<<<128, 256, 0, stream>>>(pstats, ssum, ssq);
    kbn<<<2048, 256, 0, stream>>>(out, ssum, ssq, gamma, beta);
  } else {
    kctx0<<<512, 256, 0, stream>>>(x, wq, ctx);
    kout0<<<1024, 256, 0, stream>>>(x, wq, wo, bo, ctx, out);
    kstats0<<<2048, 256, 0, stream>>>(out, ssum, ssq);
    kbn<<<2048, 256, 0, stream>>>(out, ssum, ssq, gamma, beta);
  }
}

// Round 8
// 234.135 us; speedup vs baseline: 7.7977x; 1.0557x over previous
//
#include <hip/hip_runtime.h>

typedef __attribute__((ext_vector_type(8))) short bf16x8;
typedef __attribute__((ext_vector_type(4))) float f32x4;

#define SCALEQ 0.17677669529663687f  // 32^-0.5
#define EPSV 1e-5f

__device__ inline unsigned short f2bf(float f) {
  unsigned int u = __float_as_uint(f);
  return (unsigned short)((u + 0x7FFFu + ((u >> 16) & 1u)) >> 16);
}
__device__ inline unsigned int pack2(float a, float b) {
  return (unsigned int)f2bf(a) | ((unsigned int)f2bf(b) << 16);
}

// =====================================================================
// kwconv: wqkv fp32 [384][64] -> wbf bf16 [384][64]. grid 24, block 256.
// =====================================================================
__global__ __launch_bounds__(256) void kwconv(const float* __restrict__ wqkv,
                                              unsigned short* __restrict__ wbf) {
  const int i = blockIdx.x * 256 + threadIdx.x;  // 6144 threads * 4 elems
  const float4 v = *(const float4*)&wqkv[i * 4];
  *(uint2*)&wbf[i * 4] = make_uint2(pack2(v.x, v.y), pack2(v.z, v.w));
}

// =====================================================================
// ktr: x [b][c][p] fp32  ->  xsw [b][p][c] bf16, granule-swizzled:
//      slot gout of row p holds source granule gout ^ (p&7) (8 bf16/granule)
// grid 16*64=1024, block 256. LDS transpose buffer XOR-swizzled.
// =====================================================================
__global__ __launch_bounds__(256) void ktr(const float* __restrict__ x,
                                           unsigned short* __restrict__ xsw) {
  __shared__ float xl[64][256];
  const int t = threadIdx.x;
  const int b = blockIdx.x >> 6;
  const int p0 = (blockIdx.x & 63) << 8;
#pragma unroll
  for (int i = 0; i < 16; ++i) {
    int s = i * 256 + t;            // 4096 float4 slots: c = s>>6, f4 = s&63
    int c = s >> 6, f4 = s & 63;
    float4 v = *(const float4*)&x[((size_t)(b * 64 + c) << 14) + p0 + f4 * 4];
    *(float4*)&xl[c][(f4 * 4) ^ ((c >> 3) << 2)] = v;
  }
  __syncthreads();
#pragma unroll
  for (int i = 0; i < 8; ++i) {
    int a = i * 256 + t;            // 2048 granule slots: row = a>>3, gout = a&7
    int row = a >> 3, gout = a & 7;
    int gsrc = gout ^ (row & 7);
    int col = row ^ (gsrc << 2);    // same swizzle on read side
    unsigned int w0 = pack2(xl[gsrc * 8 + 0][col], xl[gsrc * 8 + 1][col]);
    unsigned int w1 = pack2(xl[gsrc * 8 + 2][col], xl[gsrc * 8 + 3][col]);
    unsigned int w2 = pack2(xl[gsrc * 8 + 4][col], xl[gsrc * 8 + 5][col]);
    unsigned int w3 = pack2(xl[gsrc * 8 + 6][col], xl[gsrc * 8 + 7][col]);
    size_t off = ((size_t)(b * 16384 + p0 + row) * 64) + gout * 8;
    *(uint4*)&xsw[off] = make_uint4(w0, w1, w2, w3);
  }
}

// =====================================================================
// kctx: barrier-free all-MFMA context kernel. grid 1024, block 256 (4 waves).
// Wave w = head w, block = 256 positions in 4 half-chunks of 64.
// Per half-chunk: GEMM1 (kv = Wkv*X, 4 N-tiles), softmax(k), stage bf16 to
// this wave's PRIVATE 8KB LDS quadrant (granule^row&7 swizzle), GEMM2
// (full 32x32 ctx quadrant set, K=64, 8 MFMA) accumulated in registers.
// NO __syncthreads anywhere; same-wave LDS ordering via lgkmcnt.
// =====================================================================
__global__ __launch_bounds__(256) void kctx(const unsigned short* __restrict__ xsw,
                                            const unsigned short* __restrict__ wbf,
                                            float* __restrict__ ctx) {
  __shared__ __align__(16) unsigned short kvb[4 * 64 * 64];  // 32KB, 8KB/wave
  const int t = threadIdx.x;
  const int l = t & 63;
  const int w = t >> 6;          // wave = head
  const int b = blockIdx.x >> 6;
  const int pt = blockIdx.x & 63;
  const int lo16 = l & 15, hi4 = l >> 4;
  unsigned short* kw = kvb + w * 4096;  // private region
  const unsigned short* xb = xsw + (size_t)(b * 16384 + pt * 256) * 64;
  const int h = w;

  // ---- A-fragments hoisted once: k rows 128+h*32.. (Mt 0,1), v rows 256+h*32..
  bf16x8 afr[4][2];
#pragma unroll
  for (int Mt = 0; Mt < 4; ++Mt) {
    int row = (Mt < 2) ? (128 + h * 32 + Mt * 16 + lo16)
                       : (256 + h * 32 + (Mt - 2) * 16 + lo16);
#pragma unroll
    for (int Ks = 0; Ks < 2; ++Ks)
      afr[Mt][Ks] = *(const bf16x8*)&wbf[row * 64 + Ks * 32 + (hi4 << 3)];
  }

  f32x4 acc2[4];
#pragma unroll
  for (int qd = 0; qd < 4; ++qd) acc2[qd] = (f32x4){0.f, 0.f, 0.f, 0.f};

  for (int hc = 0; hc < 4; ++hc) {
    // ---- GEMM1 + softmax + stage, 4 N-tiles of 16 positions
#pragma unroll
    for (int nt = 0; nt < 4; ++nt) {
      const int lp = nt * 16 + lo16;       // 0..63 local position
      const int p = hc * 64 + lp;          // 0..255 block position
      f32x4 acc[4];
#pragma unroll
      for (int Mt = 0; Mt < 4; ++Mt) acc[Mt] = (f32x4){0.f, 0.f, 0.f, 0.f};
#pragma unroll
      for (int Ks = 0; Ks < 2; ++Ks) {
        int g = Ks * 4 + hi4;
        bf16x8 bfr = *(const bf16x8*)&xb[p * 64 + ((g ^ (p & 7)) << 3)];
#pragma unroll
        for (int Mt = 0; Mt < 4; ++Mt)
          acc[Mt] = __builtin_amdgcn_mfma_f32_16x16x32_bf16(afr[Mt][Ks], bfr,
                                                            acc[Mt], 0, 0, 0);
      }
      // softmax over the 32 k-features (acc[0],acc[1]) of this position
      float m = acc[0][0];
#pragma unroll
      for (int r = 1; r < 4; ++r) m = fmaxf(m, acc[0][r]);
#pragma unroll
      for (int r = 0; r < 4; ++r) m = fmaxf(m, acc[1][r]);
      m = fmaxf(m, __shfl_xor(m, 16));
      m = fmaxf(m, __shfl_xor(m, 32));
      float s = 0.f;
#pragma unroll
      for (int Mt = 0; Mt < 2; ++Mt)
#pragma unroll
        for (int r = 0; r < 4; ++r) {
          acc[Mt][r] = __expf(acc[Mt][r] - m);
          s += acc[Mt][r];
        }
      s += __shfl_xor(s, 16);
      s += __shfl_xor(s, 32);
      const float inv = 1.f / s;
      // stage bf16 into private kvb: row = feature (0-31 k, 32-63 v)
#pragma unroll
      for (int Mt = 0; Mt < 4; ++Mt) {
#pragma unroll
        for (int r = 0; r < 4; ++r) {
          int row = ((Mt < 2) ? Mt * 16 : 32 + (Mt - 2) * 16) + hi4 * 4 + r;
          float val = (Mt < 2) ? acc[Mt][r] * inv : acc[Mt][r];
          kw[row * 64 + ((((lp >> 3) ^ (row & 7))) << 3) + (lp & 7)] = f2bf(val);
        }
      }
    }

    // ---- GEMM2: all 4 quadrants of this head's 32x32 ctx, K=64
#pragma unroll
    for (int qd = 0; qd < 4; ++qd) {
      const int arow = ((qd >> 1) << 4) + lo16;       // k feature d
      const int brow = 32 + ((qd & 1) << 4) + lo16;   // v feature e
#pragma unroll
      for (int Ks2 = 0; Ks2 < 2; ++Ks2) {
        int j8 = Ks2 * 4 + hi4;
        bf16x8 ka = *(const bf16x8*)&kw[arow * 64 + ((j8 ^ (arow & 7)) << 3)];
        bf16x8 va = *(const bf16x8*)&kw[brow * 64 + ((j8 ^ (brow & 7)) << 3)];
        acc2[qd] = __builtin_amdgcn_mfma_f32_16x16x32_bf16(ka, va, acc2[qd],
                                                           0, 0, 0);
      }
    }
  }

  // ---- one atomic pass per block; each wave owns its head entirely
#pragma unroll
  for (int qd = 0; qd < 4; ++qd) {
    const int d0 = ((qd >> 1) << 4) + hi4 * 4;
    const int e  = ((qd & 1) << 4) + lo16;
#pragma unroll
    for (int r = 0; r < 4; ++r)
      atomicAdd(&ctx[(size_t)((b * 4 + h) * 32 + d0 + r) * 32 + e],
                acc2[qd][r]);
  }
}

// =====================================================================
// kweff: Weff[b][o][h*32+d] = SCALEQ * sum_e Wo[o][h*32+e] * ctx[b][h][d][e]
//        emitted directly as bf16. grid 16, block 256
// =====================================================================
__global__ __launch_bounds__(256) void kweff(const float* __restrict__ ctx,
                                             const float* __restrict__ wo,
                                             unsigned short* __restrict__ weffbf) {
  __shared__ float ctxl[4 * 1064];  // [h][d][33] (+8 pad per h)
  const int t = threadIdx.x;
  const int b = blockIdx.x;
#pragma unroll
  for (int i = 0; i < 16; ++i) {
    int idx = i * 256 + t;
    int h = idx >> 10, d = (idx >> 5) & 31, e = idx & 31;
    ctxl[h * 1064 + d * 33 + e] = ctx[(size_t)(b * 4 + h) * 1024 + d * 32 + e];
  }
  __syncthreads();
  const int o = t >> 2, h = t & 3;
  float wr[32];
#pragma unroll
  for (int e4 = 0; e4 < 8; ++e4) {
    float4 v = *(const float4*)&wo[o * 128 + h * 32 + e4 * 4];
    wr[e4 * 4] = v.x; wr[e4 * 4 + 1] = v.y;
    wr[e4 * 4 + 2] = v.z; wr[e4 * 4 + 3] = v.w;
  }
  for (int d = 0; d < 32; ++d) {
    float s = 0.f;
#pragma unroll
    for (int e = 0; e < 32; ++e) s = fmaf(wr[e], ctxl[h * 1064 + d * 33 + e], s);
    weffbf[(size_t)b * 8192 + o * 128 + h * 32 + d] = f2bf(s * SCALEQ);
  }
}

// =====================================================================
// kout: q = softmax(Wq*X) via MFMA; y = Weff*qs + bias via MFMA;
//       per-block BN partials (NO global atomics). grid 2048, block 256
// =====================================================================
__global__ __launch_bounds__(256) void kout(const unsigned short* __restrict__ xsw,
                                            const unsigned short* __restrict__ wbf,
                                            const unsigned short* __restrict__ weffbf,
                                            const float* __restrict__ bo,
                                            float* __restrict__ y,
                                            float* __restrict__ pstats) {
  __shared__ __align__(16) unsigned short xs[128 * 64];    // 16KB
  __shared__ __align__(16) unsigned short qsl[128 * 128];  // 32KB [p][hd] swz g^=(p&15)
  const int t = threadIdx.x;
  const int l = t & 63;
  const int w = t >> 6;
  const int b = blockIdx.x >> 7;
  const int p0 = (blockIdx.x & 127) << 7;
  const int lo16 = l & 15, hi4 = l >> 4;
  const unsigned short* web = weffbf + ((size_t)b << 13);

  {  // stage xs (linear copy; swizzle pre-baked in global layout)
    const uint4* src = (const uint4*)&xsw[(size_t)(b * 16384 + p0) * 64];
    uint4* dst = (uint4*)xs;
#pragma unroll
    for (int i = 0; i < 4; ++i) dst[i * 256 + t] = src[i * 256 + t];
  }
  __syncthreads();

  // ---- GEMM-Q: wave w = head w (q rows w*32..w*32+31)
  {
    bf16x8 aq[2][2];
#pragma unroll
    for (int Mt = 0; Mt < 2; ++Mt) {
      int row = w * 32 + Mt * 16 + lo16;
#pragma unroll
      for (int Ks = 0; Ks < 2; ++Ks)
        aq[Mt][Ks] = *(const bf16x8*)&wbf[row * 64 + Ks * 32 + (hi4 << 3)];
    }
#pragma unroll
    for (int Nt = 0; Nt < 8; ++Nt) {
      const int p = Nt * 16 + lo16;
      f32x4 acc[2];
      acc[0] = (f32x4){0.f, 0.f, 0.f, 0.f};
      acc[1] = (f32x4){0.f, 0.f, 0.f, 0.f};
#pragma unroll
      for (int Ks = 0; Ks < 2; ++Ks) {
        int g = Ks * 4 + hi4;
        bf16x8 bfr = *(const bf16x8*)&xs[p * 64 + ((g ^ (p & 7)) << 3)];
#pragma unroll
        for (int Mt = 0; Mt < 2; ++Mt)
          acc[Mt] = __builtin_amdgcn_mfma_f32_16x16x32_bf16(aq[Mt][Ks], bfr,
                                                            acc[Mt], 0, 0, 0);
      }
      float m = acc[0][0];
#pragma unroll
      for (int r = 1; r < 4; ++r) m = fmaxf(m, acc[0][r]);
#pragma unroll
      for (int r = 0; r < 4; ++r) m = fmaxf(m, acc[1][r]);
      m = fmaxf(m, __shfl_xor(m, 16));
      m = fmaxf(m, __shfl_xor(m, 32));
      float s = 0.f;
#pragma unroll
      for (int Mt = 0; Mt < 2; ++Mt)
#pragma unroll
        for (int r = 0; r < 4; ++r) {
          acc[Mt][r] = __expf(acc[Mt][r] - m);
          s += acc[Mt][r];
        }
      s += __shfl_xor(s, 16);
      s += __shfl_xor(s, 32);
      const float inv = 1.f / s;
#pragma unroll
      for (int Mt = 0; Mt < 2; ++Mt) {
#pragma unroll
        for (int pr = 0; pr < 2; ++pr) {
          int hd = w * 32 + Mt * 16 + hi4 * 4 + pr * 2;
          int g = hd >> 3;
          int col = ((g ^ (p & 15)) << 3) | (hd & 7);
          *(unsigned int*)&qsl[p * 128 + col] =
              pack2(acc[Mt][pr * 2] * inv, acc[Mt][pr * 2 + 1] * inv);
        }
      }
    }
  }
  __syncthreads();

  // ---- GEMM-Y: y[o][p] = sum_hd Weff[o][hd]*qs[hd][p]; wave w: Nt {2w,2w+1}
  f32x4 accY[2][4];
#pragma unroll
  for (int nt = 0; nt < 2; ++nt)
#pragma unroll
    for (int Mt = 0; Mt < 4; ++Mt) accY[nt][Mt] = (f32x4){0.f, 0.f, 0.f, 0.f};
#pragma unroll
  for (int nt = 0; nt < 2; ++nt) {
    const int p = (w * 2 + nt) * 16 + lo16;
#pragma unroll
    for (int Ks = 0; Ks < 4; ++Ks) {
      int g = Ks * 4 + hi4;
      bf16x8 bq = *(const bf16x8*)&qsl[p * 128 + ((g ^ (p & 15)) << 3)];
#pragma unroll
      for (int Mt = 0; Mt < 4; ++Mt) {
        int o = Mt * 16 + lo16;
        bf16x8 aw = *(const bf16x8*)&web[o * 128 + (g << 3)];
        accY[nt][Mt] = __builtin_amdgcn_mfma_f32_16x16x32_bf16(aw, bq,
                                                               accY[nt][Mt], 0, 0, 0);
      }
    }
  }

  // ---- epilogue: bias, store y, accumulate per-lane BN partials
  float sacc[16], qacc[16];
#pragma unroll
  for (int i = 0; i < 16; ++i) { sacc[i] = 0.f; qacc[i] = 0.f; }
#pragma unroll
  for (int nt = 0; nt < 2; ++nt) {
    const int p = p0 + (w * 2 + nt) * 16 + lo16;
#pragma unroll
    for (int Mt = 0; Mt < 4; ++Mt) {
#pragma unroll
      for (int r = 0; r < 4; ++r) {
        int o = Mt * 16 + hi4 * 4 + r;
        float val = accY[nt][Mt][r] + bo[o];
        y[((size_t)(b * 64 + o) << 14) + p] = val;
        sacc[Mt * 4 + r] += val;
        qacc[Mt * 4 + r] += val * val;
      }
    }
  }
  // intra-wave reduce across the 16 lanes sharing an o-set
#pragma unroll
  for (int off = 1; off < 16; off <<= 1) {
#pragma unroll
    for (int i = 0; i < 16; ++i) {
      sacc[i] += __shfl_xor(sacc[i], off);
      qacc[i] += __shfl_xor(qacc[i], off);
    }
  }
  // cross-wave reduce in LDS (reuse qsl region), one coalesced row per block
  __syncthreads();  // all GEMM-Y qsl reads complete
  float* red = (float*)qsl;  // 4 waves * 128 floats
  if (lo16 == 0) {
#pragma unroll
    for (int i = 0; i < 16; ++i) {
      int o = (i >> 2) * 16 + hi4 * 4 + (i & 3);
      red[w * 128 + o] = sacc[i];
      red[w * 128 + 64 + o] = qacc[i];
    }
  }
  __syncthreads();
  if (t < 128) {
    float s = red[t] + red[128 + t] + red[256 + t] + red[384 + t];
    pstats[(size_t)blockIdx.x * 128 + t] = s;
  }
}

// =====================================================================
// kred: reduce pstats[2048][128] -> ssum[64], ssq[64]. grid 128, block 256
// =====================================================================
__global__ __launch_bounds__(256) void kred(const float* __restrict__ pstats,
                                            float* __restrict__ ssum,
                                            float* __restrict__ ssq) {
  const int t = threadIdx.x;
  const int which = blockIdx.x >> 6;  // 0: sum, 1: sumsq
  const int o = blockIdx.x & 63;
  const int base = which * 64 + o;
  float s = 0.f;
#pragma unroll
  for (int i = 0; i < 8; ++i)
    s += pstats[(size_t)(i * 256 + t) * 128 + base];
#pragma unroll
  for (int off = 32; off > 0; off >>= 1) s += __shfl_down(s, off);
  __shared__ float ls[4];
  if ((t & 63) == 0) ls[t >> 6] = s;
  __syncthreads();
  if (t == 0) {
    float r = ls[0] + ls[1] + ls[2] + ls[3];
    if (which) ssq[o] = r; else ssum[o] = r;
  }
}

// =====================================================================
// kbn: in-place BatchNorm apply (grid 2048, block 256)
// =====================================================================
__global__ __launch_bounds__(256) void kbn(float* __restrict__ y,
                                           const float* __restrict__ ssum,
                                           const float* __restrict__ ssq,
                                           const float* __restrict__ gamma,
                                           const float* __restrict__ beta) {
  const int t = threadIdx.x;
  const size_t base = (size_t)blockIdx.x * 8192;
  const int o = (blockIdx.x >> 1) & 63;
  const float invn = 1.f / 262144.f;
  const float mean = ssum[o] * invn;
  const float var = ssq[o] * invn - mean * mean;
  const float g = gamma[o] * rsqrtf(var + EPSV);
  const float sh = beta[o] - mean * g;
#pragma unroll
  for (int it = 0; it < 8; ++it) {
    float4 v = *(float4*)&y[base + it * 1024 + t * 4];
    v.x = v.x * g + sh;
    v.y = v.y * g + sh;
    v.z = v.z * g + sh;
    v.w = v.w * g + sh;
    *(float4*)&y[base + it * 1024 + t * 4] = v;
  }
}

// =====================================================================
// ============ Fallback path (round-0, known-correct) ==================
// =====================================================================
__global__ __launch_bounds__(256) void kctx0(const float* __restrict__ x,
                                             const float* __restrict__ wq,
                                             float* __restrict__ ctxT) {
  __shared__ float kT[32 * 256];
  __shared__ float vT[32 * 256];
  const int t = threadIdx.x;
  const int b = blockIdx.x >> 5;
  const int tile = blockIdx.x & 31;
  const int d0 = (t & 15) << 1;
  const int e0 = (t >> 4) << 1;
  float acc[4][2][2];
#pragma unroll
  for (int h = 0; h < 4; ++h)
#pragma unroll
    for (int i = 0; i < 2; ++i)
#pragma unroll
      for (int j = 0; j < 2; ++j) acc[h][i][j] = 0.f;
  for (int chunk = 0; chunk < 2; ++chunk) {
    const int p = (tile << 9) + (chunk << 8) + t;
    float xr[64];
#pragma unroll
    for (int c = 0; c < 64; ++c) xr[c] = x[((size_t)(b * 64 + c) << 14) + p];
#pragma unroll
    for (int h = 0; h < 4; ++h) {
      float kk[32];
#pragma unroll
      for (int i = 0; i < 32; ++i) {
        const float* wr = wq + (128 + h * 32 + i) * 64;
        float a = 0.f;
#pragma unroll
        for (int c = 0; c < 64; ++c) a = fmaf(wr[c], xr[c], a);
        kk[i] = a;
      }
      float m = kk[0];
#pragma unroll
      for (int i = 1; i < 32; ++i) m = fmaxf(m, kk[i]);
      float s = 0.f;
#pragma unroll
      for (int i = 0; i < 32; ++i) { kk[i] = __expf(kk[i] - m); s += kk[i]; }
      const float inv = 1.f / s;
      float vv[32];
#pragma unroll
      for (int i = 0; i < 32; ++i) {
        const float* wr = wq + (256 + h * 32 + i) * 64;
        float a = 0.f;
#pragma unroll
        for (int c = 0; c < 64; ++c) a = fmaf(wr[c], xr[c], a);
        vv[i] = a;
      }
      __syncthreads();
#pragma unroll
      for (int i = 0; i < 32; ++i) kT[i * 256 + (t ^ (2 * i))] = kk[i] * inv;
#pragma unroll
      for (int i = 0; i < 32; ++i) vT[i * 256 + t] = vv[i];
      __syncthreads();
#pragma unroll 2
      for (int p2 = 0; p2 < 256; p2 += 2) {
        const float2 k0 = *(const float2*)&kT[d0 * 256 + (p2 ^ (2 * d0))];
        const float2 k1 = *(const float2*)&kT[(d0 + 1) * 256 + (p2 ^ (2 * (d0 + 1)))];
        const float2 v0 = *(const float2*)&vT[e0 * 256 + p2];
        const float2 v1 = *(const float2*)&vT[(e0 + 1) * 256 + p2];
        acc[h][0][0] += k0.x * v0.x + k0.y * v0.y;
        acc[h][0][1] += k0.x * v1.x + k0.y * v1.y;
        acc[h][1][0] += k1.x * v0.x + k1.y * v0.y;
        acc[h][1][1] += k1.x * v1.x + k1.y * v1.y;
      }
    }
  }
#pragma unroll
  for (int h = 0; h < 4; ++h)
#pragma unroll
    for (int i = 0; i < 2; ++i)
#pragma unroll
      for (int j = 0; j < 2; ++j)
        atomicAdd(&ctxT[(((b * 4 + h) * 32) + (e0 + j)) * 32 + (d0 + i)],
                  acc[h][i][j]);
}

__global__ __launch_bounds__(256) void kout0(const float* __restrict__ x,
                                             const float* __restrict__ wq,
                                             const float* __restrict__ wo,
                                             const float* __restrict__ bo,
                                             const float* __restrict__ ctxT,
                                             float* __restrict__ y) {
  __shared__ float cl[4096];
  const int t = threadIdx.x;
  const int b = blockIdx.x >> 6;
  const int tile = blockIdx.x & 63;
  const int p = (tile << 8) + t;
#pragma unroll
  for (int i = 0; i < 16; ++i) cl[i * 256 + t] = ctxT[(b << 12) + i * 256 + t];
  __syncthreads();
  float xr[64];
#pragma unroll
  for (int c = 0; c < 64; ++c) xr[c] = x[((size_t)(b * 64 + c) << 14) + p];
  float y0[64];
#pragma unroll
  for (int o = 0; o < 64; ++o) y0[o] = 0.f;
  for (int h = 0; h < 4; ++h) {
    float q[32];
#pragma unroll
    for (int i = 0; i < 32; ++i) {
      const float* wr = wq + (h * 32 + i) * 64;
      float a = 0.f;
#pragma unroll
      for (int c = 0; c < 64; ++c) a = fmaf(wr[c], xr[c], a);
      q[i] = a;
    }
    float m = q[0];
#pragma unroll
    for (int i = 1; i < 32; ++i) m = fmaxf(m, q[i]);
    float s = 0.f;
#pragma unroll
    for (int i = 0; i < 32; ++i) { q[i] = __expf(q[i] - m); s += q[i]; }
    const float inv = SCALEQ / s;
#pragma unroll
    for (int i = 0; i < 32; ++i) q[i] *= inv;
    float oh[32];
#pragma unroll
    for (int e = 0; e < 32; ++e) {
      const float* cr = &cl[(h * 32 + e) * 32];
      float a = 0.f;
#pragma unroll
      for (int d = 0; d < 32; ++d) a = fmaf(cr[d], q[d], a);
      oh[e] = a;
    }
#pragma unroll
    for (int o = 0; o < 64; ++o) {
      const float* wr = wo + o * 128 + h * 32;
      float a = y0[o];
#pragma unroll
      for (int e = 0; e < 32; ++e) a = fmaf(wr[e], oh[e], a);
      y0[o] = a;
    }
  }
#pragma unroll
  for (int o = 0; o < 64; ++o)
    y[((size_t)(b * 64 + o) << 14) + p] = y0[o] + bo[o];
}

__global__ __launch_bounds__(256) void kstats0(const float* __restrict__ y,
                                               float* __restrict__ ssum,
                                               float* __restrict__ ssq) {
  const int t = threadIdx.x;
  const size_t base = (size_t)blockIdx.x * 8192;
  const int o = (blockIdx.x >> 1) & 63;
  float s = 0.f, q = 0.f;
#pragma unroll
  for (int it = 0; it < 8; ++it) {
    const float4 v = *(const float4*)&y[base + it * 1024 + t * 4];
    s += v.x + v.y + v.z + v.w;
    q += v.x * v.x + v.y * v.y + v.z * v.z + v.w * v.w;
  }
#pragma unroll
  for (int off = 32; off > 0; off >>= 1) {
    s += __shfl_down(s, off);
    q += __shfl_down(q, off);
  }
  __shared__ float ls[4], lq[4];
  if ((t & 63) == 0) { ls[t >> 6] = s; lq[t >> 6] = q; }
  __syncthreads();
  if (t == 0) {
    atomicAdd(&ssum[o], ls[0] + ls[1] + ls[2] + ls[3]);
    atomicAdd(&ssq[o], lq[0] + lq[1] + lq[2] + lq[3]);
  }
}

// =====================================================================
extern "C" void kernel_launch(void* const* d_in, const int* in_sizes, int n_in,
                              void* d_out, int out_size, void* d_ws, size_t ws_size,
                              hipStream_t stream) {
  (void)in_sizes; (void)n_in; (void)out_size;
  const float* x     = (const float*)d_in[0];
  const float* wq    = (const float*)d_in[1];
  const float* wo    = (const float*)d_in[2];
  const float* bo    = (const float*)d_in[3];
  const float* gamma = (const float*)d_in[4];
  const float* beta  = (const float*)d_in[5];
  float* out = (float*)d_out;

  // workspace layout (bytes):
  // ctx    @ 0        : 262144   (65536 f32)
  // ssum   @ 262144   : 256      (64 f32)
  // ssq    @ 262400   : 256      (64 f32)
  // weffbf @ 262656   : 262144   (16*64*128 bf16)
  // wbf    @ 524800   : 49152    (384*64 bf16)
  // pstats @ 573952   : 1048576  (2048*128 f32)
  // xsw    @ 1622528  : 33554432 (16*16384*64 bf16)
  float* ctx  = (float*)d_ws;
  float* ssum = (float*)((char*)d_ws + 262144);
  float* ssq  = (float*)((char*)d_ws + 262400);
  unsigned short* weffbf = (unsigned short*)((char*)d_ws + 262656);
  unsigned short* wbf    = (unsigned short*)((char*)d_ws + 524800);
  float* pstats          = (float*)((char*)d_ws + 573952);
  unsigned short* xsw    = (unsigned short*)((char*)d_ws + 1622528);
  const size_t need = 1622528 + (size_t)16 * 16384 * 64 * 2;

  hipMemsetAsync(d_ws, 0, 262656, stream);  // ctx + ssum + ssq
  if (ws_size >= need) {
    kwconv<<<24, 256, 0, stream>>>(wq, wbf);
    ktr<<<1024, 256, 0, stream>>>(x, xsw);
    kctx<<<1024, 256, 0, stream>>>(xsw, wbf, ctx);
    kweff<<<16, 256, 0, stream>>>(ctx, wo, weffbf);
    kout<<<2048, 256, 0, stream>>>(xsw, wbf, weffbf, bo, out, pstats);
    kred<<<128, 256, 0, stream>>>(pstats, ssum, ssq);
    kbn<<<2048, 256, 0, stream>>>(out, ssum, ssq, gamma, beta);
  } else {
    kctx0<<<512, 256, 0, stream>>>(x, wq, ctx);
    kout0<<<1024, 256, 0, stream>>>(x, wq, wo, bo, ctx, out);
    kstats0<<<2048, 256, 0, stream>>>(out, ssum, ssq);
    kbn<<<2048, 256, 0, stream>>>(out, ssum, ssq, gamma, beta);
  }
}